// Round 5
// baseline (2374.465 us; speedup 1.0000x reference)
//
#include <hip/hip_runtime.h>

// GraphMoE dual router: encoder -> routers -> 8 GraphConv experts (3 layers) -> sparse combine.
// R1: agg latency fix: half-wave/node, 16B/lane, 8 row-gathers in flight.
// R2/R3: ushort cols, top-2 sparsity on layer-2.
// R4: 1-atomic CSR (perm), atomic-free scatter, gll16+XOR-swizzle GEMM, rank-disjoint outR. 2168us.
// R5 FAILED (2378): role-fused gemm||agg — fused kernel's GEMM footprint caps agg occupancy.
// R6 FAILED (2597): agg column-slicing: 64B gathers destroyed L2 reuse (FETCH 687->808MB).
// R7 FAILED (2245): 16-deep unroll + masked tail: VGPR 40->64, occ 57->39%, VALU 2x. REVERTED.
//   A/B lesson: L2-miss rate 3.45->3.13 TB/s tracked occupancy -> agg still latency-limited,
//   not fabric-capped. Cheapest occupancy lever = load balance, not ILP.
// R8 (this round): DEGREE-SORTED node order. Block = 8 half-wave nodes, Poisson(32) degrees
//   -> lifetime = max-of-8 ~ 1.45x mean ~ 30% wasted slots (matches occ 57%). Counting-sort
//   nodes by in-degree (descending; 3 tiny kernels ~20us), feed as list to all full aggs;
//   build_lists consumes sorted order -> selected lists approx sorted too. Inner loop = R4.
//   Predict: full agg occ 57->~72%, dur 199->~165us, FETCH unchanged. Total ~1950.

#define NN 50000
#define EE 1600000
#define GG 64
#define HH 256
#define NEXP 8
#define LAY 3
#define KD 512          // concat K = [z | agg]
#define MT 128          // GEMM row tile per block
#define BK 64           // GEMM K tile
#define GB 391          // (NN + MT - 1) / MT
#define AGB 6250        // NN / 8 agg blocks (8 half-waves each)
#define MPAD 50048L     // 391 * 128
#define DBIN 128        // degree-sort bins

typedef __attribute__((ext_vector_type(8))) short bf16x8;
typedef __attribute__((ext_vector_type(8))) unsigned short u16x8;
typedef __attribute__((ext_vector_type(4))) float f32x4;

__device__ __forceinline__ float bf2f(unsigned short u) {
    union { unsigned int i; float f; } v; v.i = ((unsigned int)u) << 16; return v.f;
}
__device__ __forceinline__ unsigned short f2bf(float f) {
    union { unsigned int i; float f; } v; v.f = f;
    unsigned int r = (v.i + 0x7FFFu + ((v.i >> 16) & 1u)) >> 16;
    return (unsigned short)r;
}
__device__ __forceinline__ void gll16(unsigned short* l, const unsigned short* g) {
    __builtin_amdgcn_global_load_lds((__attribute__((address_space(1))) void*)g,
                                     (__attribute__((address_space(3))) void*)l, 16, 0, 0);
}

// ---------------- encoder: h = relu(x[:,4:10] @ W_enc + b_enc), bf16 into Ash cols 0..255
__global__ void encoder_kernel(const float* __restrict__ x, const float* __restrict__ W,
                               const float* __restrict__ b, unsigned short* __restrict__ out) {
    int n = blockIdx.x, j = threadIdx.x;
    float acc = b[j];
#pragma unroll
    for (int i = 0; i < 6; i++) acc += x[n * 10 + 4 + i] * W[i * HH + j];
    acc = fmaxf(acc, 0.f);
    out[(long)n * KD + j] = f2bf(acc);
}

// ---------------- weight packing: Bt[(e*3+l)][n][k] bf16, k<256 -> W_self, k>=256 -> W_neigh
__global__ void pack_experts(const float* __restrict__ Wself, const float* __restrict__ Wneigh,
                             unsigned short* __restrict__ Bt) {
    int idx = blockIdx.x * 256 + threadIdx.x;          // (e,l,k,n), n fastest
    int n = idx & 255; int r = idx >> 8;
    int k = r & 511; r >>= 9;
    int l = r % LAY; int e = r / LAY;
    float v = (k < 256) ? Wself[(((e * LAY + l) * HH) + k) * HH + n]
                        : Wneigh[(((e * LAY + l) * HH) + (k - 256)) * HH + n];
    Bt[(((long)(e * LAY + l) * HH + n) * KD) + k] = f2bf(v);
}

__global__ void pack_ws1(const float* __restrict__ W, unsigned short* __restrict__ Bt) {
    int idx = blockIdx.x * 256 + threadIdx.x;
    int n = idx & 255; int k = idx >> 8;
    Bt[(long)n * HH + k] = f2bf(W[k * HH + n]);
}

// ---------------- degree pass: ONE atomic per edge; returned old value = within-row slot.
__global__ void degp_kernel(const int* __restrict__ dst, int* __restrict__ deg,
                            unsigned short* __restrict__ perm) {
    int e = blockIdx.x * 256 + threadIdx.x;
    if (e < EE) perm[e] = (unsigned short)atomicAdd(&deg[dst[e]], 1);  // max in-degree << 65536
}

// ---------------- per-graph edge histogram via ballot: 1 ballot/edge, no per-edge atomics.
#define HBLK 128
#define HITER ((EE + HBLK * 256 - 1) / (HBLK * 256))
__global__ void hist2_kernel(const int* __restrict__ src, const int* __restrict__ batch,
                             int* __restrict__ ecnt) {
    __shared__ int h[GG];
    if (threadIdx.x < GG) h[threadIdx.x] = 0;
    __syncthreads();
    int lane = threadIdx.x & 63;
    int gid = blockIdx.x * 256 + threadIdx.x;
    int cnt = 0;
    for (int it = 0; it < HITER; it++) {
        long e = (long)it * (HBLK * 256) + gid;
        int g = (e < EE) ? batch[src[e]] : -1;
        for (int gg = 0; gg < GG; gg++) {
            unsigned long long m = __ballot(g == gg);
            if (lane == gg) cnt += (int)__popcll(m);
        }
    }
    atomicAdd(&h[lane], cnt);
    __syncthreads();
    if (threadIdx.x < GG && h[threadIdx.x]) atomicAdd(&ecnt[threadIdx.x], h[threadIdx.x]);
}

// ---------------- degree counting sort (descending): bins, scan, scatter
__global__ void dhist_kernel(const int* __restrict__ deg, int* __restrict__ dh) {
    int n = blockIdx.x * 256 + threadIdx.x;
    if (n < NN) {
        int d = deg[n]; if (d > DBIN - 1) d = DBIN - 1;
        atomicAdd(&dh[(DBIN - 1) - d], 1);      // descending degree
    }
}
__global__ void dscan_kernel(const int* __restrict__ dh, int* __restrict__ dcur) {
    if (threadIdx.x == 0) {
        int run = 0;
        for (int i = 0; i < DBIN; i++) { dcur[i] = run; run += dh[i]; }
    }
}
__global__ void dorder_kernel(const int* __restrict__ deg, int* __restrict__ dcur,
                              int* __restrict__ order) {
    int n = blockIdx.x * 256 + threadIdx.x;
    if (n < NN) {
        int d = deg[n]; if (d > DBIN - 1) d = DBIN - 1;
        int p = atomicAdd(&dcur[(DBIN - 1) - d], 1);
        order[p] = n;
    }
}

// ---------------- structural router per graph; node count via binary search on sorted batch
__global__ void stru_kernel(const int* __restrict__ batch, const int* __restrict__ ecnt,
                            const float* __restrict__ Wt1, const float* __restrict__ bt1,
                            const float* __restrict__ Wt2, const float* __restrict__ bt2,
                            float* __restrict__ strug) {
    __shared__ float t[HH];
    __shared__ int nc;
    int g = blockIdx.x, j = threadIdx.x;
    if (j == 0) {
        int lo = 0, hi = NN;
        while (lo < hi) { int mid = (lo + hi) >> 1; if (batch[mid] < g) lo = mid + 1; else hi = mid; }
        int s = lo; lo = 0; hi = NN;
        while (lo < hi) { int mid = (lo + hi) >> 1; if (batch[mid] < g + 1) lo = mid + 1; else hi = mid; }
        nc = lo - s;
    }
    __syncthreads();
    float nf = log1pf((float)nc);
    float ef = log1pf((float)ecnt[g]);
    float v = nf * Wt1[j] + ef * Wt1[HH + j] + bt1[j];
    t[j] = fmaxf(v, 0.f);
    __syncthreads();
    if (j < 8) {
        float sum = bt2[j];
        for (int k = 0; k < HH; k++) sum += t[k] * Wt2[k * 8 + j];
        strug[g * 8 + j] = sum;
    }
}

// single block, 1024 threads; shuffle-based inclusive scan
__global__ void scan_kernel(const int* __restrict__ deg, int* __restrict__ rowstart) {
    __shared__ int wsum[16];
    __shared__ int carry_s;
    int tid = threadIdx.x;
    int wid = tid >> 6, lane = tid & 63;
    if (tid == 0) carry_s = 0;
    __syncthreads();
    for (int base = 0; base < NN; base += 1024) {
        int i = base + tid;
        int v = (i < NN) ? deg[i] : 0;
        int sc = v;
#pragma unroll
        for (int off = 1; off < 64; off <<= 1) {
            int t = __shfl_up(sc, off, 64);
            if (lane >= off) sc += t;
        }
        if (lane == 63) wsum[wid] = sc;
        __syncthreads();
        int carry = carry_s;
        int prev = 0;
        for (int w = 0; w < wid; w++) prev += wsum[w];
        int excl = carry + prev + sc - v;
        if (i < NN) rowstart[i] = excl;
        __syncthreads();
        if (tid == 1023) carry_s = carry + prev + sc;
    }
    __syncthreads();
    if (tid == 0) rowstart[NN] = carry_s;
}

// ---------------- atomic-free scatter: position = rowstart[dst] + perm
__global__ void scatter2_kernel(const int* __restrict__ src, const int* __restrict__ dst,
                                const unsigned short* __restrict__ perm,
                                const int* __restrict__ rowstart,
                                unsigned short* __restrict__ cols) {
    int e = blockIdx.x * 256 + threadIdx.x;
    if (e < EE) cols[rowstart[dst[e]] + (int)perm[e]] = (unsigned short)src[e];
}

// ---------------- aggregation (R4 form): Z[nid,256:512] = sum_{in-nb} Z[src,0:256]
// half-wave (32 lanes) per node, 16B/lane (512B/row-gather), unroll x8 -> 8 row-gathers
// in flight. listp + lstride: degree-sorted order (lstride=0) or per-expert list (NN).
__global__ void agg_kernel(unsigned short* __restrict__ base, long estride,
                           const int* __restrict__ rowstart, const unsigned short* __restrict__ cols,
                           const int* __restrict__ listp, long lstride,
                           const int* __restrict__ cntp) {
    unsigned short* Z = base + (long)blockIdx.y * estride;
    int half = threadIdx.x >> 5;               // 0..7
    int lane = threadIdx.x & 31;
    int idx = blockIdx.x * 8 + half;
    int limit = cntp ? cntp[blockIdx.y] : NN;
    if (idx >= limit) return;                  // half-wave uniform
    int nid = listp ? (listp[lstride * blockIdx.y + idx] & 0xFFFF) : idx;
    int s = rowstart[nid], e = rowstart[nid + 1];
    float acc[8] = {0.f, 0.f, 0.f, 0.f, 0.f, 0.f, 0.f, 0.f};
    int i = s;
    for (; i + 8 <= e; i += 8) {
        int c[8];
#pragma unroll
        for (int u = 0; u < 8; u++) c[u] = (int)cols[i + u];
        u16x8 v[8];
#pragma unroll
        for (int u = 0; u < 8; u++) v[u] = *(const u16x8*)&Z[(long)c[u] * KD + lane * 8];
#pragma unroll
        for (int u = 0; u < 8; u++)
#pragma unroll
            for (int j = 0; j < 8; j++) acc[j] += bf2f(v[u][j]);
    }
    for (; i < e; i++) {
        int c = (int)cols[i];
        u16x8 v = *(const u16x8*)&Z[(long)c * KD + lane * 8];
#pragma unroll
        for (int j = 0; j < 8; j++) acc[j] += bf2f(v[j]);
    }
    u16x8 o;
#pragma unroll
    for (int j = 0; j < 8; j++) o[j] = f2bf(acc[j]);
    *(u16x8*)&Z[(long)nid * KD + 256 + lane * 8] = o;
}

// ---------------- semantic router tail + softmax + top-2 + renormalize (wave per node)
__global__ void route_kernel(const unsigned short* __restrict__ T, const float* __restrict__ Ws2,
                             const float* __restrict__ bs2, const float* __restrict__ strug,
                             const int* __restrict__ batch, float* __restrict__ sparse,
                             int* __restrict__ topi) {
    int nid = blockIdx.x * 4 + (threadIdx.x >> 6);
    if (nid >= NN) return;
    int lane = threadIdx.x & 63;
    float s[8];
#pragma unroll
    for (int j = 0; j < 8; j++) s[j] = 0.f;
    ushort4 t4 = *(const ushort4*)&T[(long)nid * HH + lane * 4];
    float tv[4] = { bf2f(t4.x), bf2f(t4.y), bf2f(t4.z), bf2f(t4.w) };
#pragma unroll
    for (int kk = 0; kk < 4; kk++) {
        int k = lane * 4 + kk;
#pragma unroll
        for (int j = 0; j < 8; j++) s[j] += tv[kk] * Ws2[k * 8 + j];
    }
#pragma unroll
    for (int off = 32; off >= 1; off >>= 1) {
#pragma unroll
        for (int j = 0; j < 8; j++) s[j] += __shfl_xor(s[j], off, 64);
    }
    int g = batch[nid];
    float p[8], mx = -1e30f;
#pragma unroll
    for (int j = 0; j < 8; j++) {
        p[j] = 0.5f * (s[j] + bs2[j] + strug[g * 8 + j]);
        mx = fmaxf(mx, p[j]);
    }
    float ex[8];
#pragma unroll
    for (int j = 0; j < 8; j++) ex[j] = expf(p[j] - mx);
    int i1 = 0;
#pragma unroll
    for (int j = 1; j < 8; j++) if (ex[j] > ex[i1]) i1 = j;
    int i2 = (i1 == 0) ? 1 : 0;
#pragma unroll
    for (int j = 0; j < 8; j++) if (j != i1 && ex[j] > ex[i2]) i2 = j;
    float r = 1.f / (ex[i1] + ex[i2]);
    if (lane == 0) topi[nid] = i1 | (i2 << 8);
    if (lane < 8)
        sparse[(long)nid * 8 + lane] = (lane == i1) ? ex[i1] * r : (lane == i2) ? ex[i2] * r : 0.f;
}

// ---------------- per-expert selected-node lists; consumes DEGREE-SORTED order so lists
// come out approx degree-sorted. Entries packed n | rank<<16.
__global__ void build_lists(const float* __restrict__ sparse, const int* __restrict__ topi,
                            const int* __restrict__ order,
                            int* __restrict__ cnt, int* __restrict__ lists) {
    __shared__ int lc[NEXP], lb[NEXP];
    int tid = threadIdx.x;
    if (tid < NEXP) lc[tid] = 0;
    __syncthreads();
    int gid = blockIdx.x * 256 + tid;
    int n = (gid < NN) ? order[gid] : -1;
    int le_[2], pk_[2], ps_[2];
    int cc = 0;
    if (n >= 0) {
        int t1 = topi[n] & 0xFF;
#pragma unroll
        for (int e = 0; e < NEXP; e++) {
            if (sparse[(long)n * 8 + e] > 0.f && cc < 2) {
                le_[cc] = e;
                pk_[cc] = n | ((e == t1) ? 0 : (1 << 16));
                ps_[cc] = atomicAdd(&lc[e], 1);
                cc++;
            }
        }
    }
    __syncthreads();
    if (tid < NEXP) lb[tid] = atomicAdd(&cnt[tid], lc[tid]);
    __syncthreads();
    for (int c = 0; c < cc; c++)
        lists[(long)le_[c] * NN + lb[le_[c]] + ps_[c]] = pk_[c];
}

// ---------------- MFMA GEMM: C[M,256] = A[M,K]_bf16 @ Bt[256,K]_bf16 (+bias)
// blockIdx.y = expert slot. gll16 staging, linear LDS + chunk^(row&7) XOR swizzle.
// MODE 0: relu, store bf16 (stride ldz). MODE 1: rows from packed list; store
// w * (acc+bias) bf16 into rank-disjoint outR planes.
template <int MODE>
__global__ __launch_bounds__(256, 2) void gemm_kernel(
    const unsigned short* __restrict__ A, long ae, int lda, int K,
    const unsigned short* __restrict__ Bt, long bte,
    const float* __restrict__ bias, int be_s,
    void* __restrict__ outp, long oe, int ldz,
    const float* __restrict__ sparse, int e0,
    const int* __restrict__ listp, const int* __restrict__ cntp) {
    __shared__ __align__(16) unsigned short Alds[MT * 64];
    __shared__ __align__(16) unsigned short Blds[HH * 64];
    __shared__ int nodeids[MT];
    const int el = blockIdx.y;
    const unsigned short* Ae = A + (long)el * ae;
    const unsigned short* Bte = Bt + (long)el * bte;
    const float* be = bias + (long)el * be_s;
    const int tid = threadIdx.x;
    const int wave = tid >> 6, lane = tid & 63;
    const int m = lane & 15, q = lane >> 4;
    const long row0 = (long)blockIdx.x * MT;

    if constexpr (MODE == 1) {
        int limit = cntp[el];
        if (row0 >= limit) return;              // uniform exit
        if (tid < MT) {
            long rr = row0 + tid;
            nodeids[tid] = (rr < limit) ? listp[(long)el * NN + rr] : -1;
        }
        __syncthreads();
    }

    const unsigned short* asrc[4];
#pragma unroll
    for (int i = 0; i < 4; i++) {
        int slot = tid + 256 * i;
        int r = slot >> 3, cg = (slot & 7) ^ (r & 7);
        long arow;
        if constexpr (MODE == 0) {
            arow = row0 + r;                    // padded rows < MPAD: garbage, masked on store
        } else {
            int v = nodeids[r];
            arow = (v >= 0) ? (v & 0xFFFF) : 0;
        }
        asrc[i] = Ae + arow * (long)lda + cg * 8;
    }
    const unsigned short* bsrc[8];
#pragma unroll
    for (int i = 0; i < 8; i++) {
        int slot = tid + 256 * i;
        int r = slot >> 3, cg = (slot & 7) ^ (r & 7);
        bsrc[i] = Bte + (long)r * K + cg * 8;
    }

    f32x4 acc[2][16];
#pragma unroll
    for (int i = 0; i < 2; i++)
#pragma unroll
        for (int j = 0; j < 16; j++) acc[i][j] = (f32x4){0.f, 0.f, 0.f, 0.f};

    const int swz = (m & 7) << 3;
    for (int k0 = 0; k0 < K; k0 += BK) {
#pragma unroll
        for (int i = 0; i < 4; i++) gll16(&Alds[(tid + 256 * i) * 8], asrc[i] + k0);
#pragma unroll
        for (int i = 0; i < 8; i++) gll16(&Blds[(tid + 256 * i) * 8], bsrc[i] + k0);
        __syncthreads();
#pragma unroll
        for (int kk = 0; kk < BK; kk += 32) {
            const int ch8 = (((kk >> 3) + q) << 3) ^ swz;
            const int ao = (wave * 32 + m) * 64 + ch8;
            bf16x8 a0 = *(const bf16x8*)&Alds[ao];
            bf16x8 a1 = *(const bf16x8*)&Alds[ao + 16 * 64];
#pragma unroll
            for (int ct = 0; ct < 16; ct++) {
                bf16x8 b = *(const bf16x8*)&Blds[(ct * 16 + m) * 64 + ch8];
                acc[0][ct] = __builtin_amdgcn_mfma_f32_16x16x32_bf16(a0, b, acc[0][ct], 0, 0, 0);
                acc[1][ct] = __builtin_amdgcn_mfma_f32_16x16x32_bf16(a1, b, acc[1][ct], 0, 0, 0);
            }
        }
        __syncthreads();
    }
    // epilogue: D layout col = lane&15, row = (lane>>4)*4 + reg
#pragma unroll
    for (int mt = 0; mt < 2; mt++) {
        int rtile = wave * 32 + mt * 16 + q * 4;
        if constexpr (MODE == 0) {
            unsigned short* oute = (unsigned short*)outp + (long)el * oe;
            long rbase = row0 + rtile;
#pragma unroll
            for (int ct = 0; ct < 16; ct++) {
                int col = ct * 16 + m;
                float bv = be[col];
#pragma unroll
                for (int r = 0; r < 4; r++) {
                    long grow = rbase + r;
                    if (grow < NN) {
                        float v = fmaxf(acc[mt][ct][r] + bv, 0.f);
                        oute[grow * ldz + col] = f2bf(v);
                    }
                }
            }
        } else {
            unsigned short* outR = (unsigned short*)outp;
            int v4[4]; float w4[4];
#pragma unroll
            for (int r = 0; r < 4; r++) {
                v4[r] = nodeids[rtile + r];
                w4[r] = (v4[r] >= 0) ? sparse[(long)(v4[r] & 0xFFFF) * 8 + e0 + el] : 0.f;
            }
#pragma unroll
            for (int ct = 0; ct < 16; ct++) {
                int col = ct * 16 + m;
                float bv = be[col];
#pragma unroll
                for (int r = 0; r < 4; r++) {
                    if (v4[r] >= 0) {
                        long nid = v4[r] & 0xFFFF;
                        long rank = (v4[r] >> 16) & 1;
                        outR[(rank * MPAD + nid) * HH + col] = f2bf(w4[r] * (acc[mt][ct][r] + bv));
                    }
                }
            }
        }
    }
}

// ---------------- final combine: out = rank0 + rank1 (weights already applied)
__global__ void combine_kernel(const unsigned short* __restrict__ outR, float* __restrict__ out) {
    long base = ((long)blockIdx.x * 256 + threadIdx.x) * 8;
    u16x8 r0 = *(const u16x8*)&outR[base];
    u16x8 r1 = *(const u16x8*)&outR[MPAD * HH + base];
    f32x4 lo, hi;
#pragma unroll
    for (int j = 0; j < 4; j++) lo[j] = bf2f(r0[j]) + bf2f(r1[j]);
#pragma unroll
    for (int j = 0; j < 4; j++) hi[j] = bf2f(r0[j + 4]) + bf2f(r1[j + 4]);
    *(f32x4*)&out[base] = lo;
    *(f32x4*)&out[base + 4] = hi;
}

extern "C" void kernel_launch(void* const* d_in, const int* in_sizes, int n_in,
                              void* d_out, int out_size, void* d_ws, size_t ws_size,
                              hipStream_t stream) {
    const float* x     = (const float*)d_in[0];
    const int*   ei    = (const int*)d_in[1];
    const int*   src   = ei;
    const int*   dst   = ei + EE;
    const int*   batch = (const int*)d_in[2];
    const float* W_enc = (const float*)d_in[3];
    const float* b_enc = (const float*)d_in[4];
    const float* Ws1   = (const float*)d_in[5];
    const float* bs1   = (const float*)d_in[6];
    const float* Ws2   = (const float*)d_in[7];
    const float* bs2   = (const float*)d_in[8];
    const float* Wt1   = (const float*)d_in[9];
    const float* bt1   = (const float*)d_in[10];
    const float* Wt2   = (const float*)d_in[11];
    const float* bt2   = (const float*)d_in[12];
    const float* W_self  = (const float*)d_in[13];
    const float* W_neigh = (const float*)d_in[14];
    const float* b_exp   = (const float*)d_in[15];
    float* out = (float*)d_out;

    char* ws = (char*)d_ws;
    size_t off = 0;
    auto alloc = [&](size_t b) { size_t p = off; off = (off + b + 255) & ~(size_t)255; return ws + p; };

    unsigned short* Ash  = (unsigned short*)alloc((size_t)MPAD * KD * 2);
    unsigned short* outR = (unsigned short*)alloc((size_t)2 * MPAD * HH * 2);
    unsigned short* Tbuf = outR;  // alias: router hidden consumed before outR first written
    unsigned short* BtE = (unsigned short*)alloc((size_t)NEXP * LAY * HH * KD * 2);
    unsigned short* Bt1 = (unsigned short*)alloc((size_t)HH * HH * 2);
    float* sparse  = (float*)alloc((size_t)NN * 8 * 4);
    int* topi      = (int*)alloc((size_t)NN * 4);
    float* strug   = (float*)alloc((size_t)GG * 8 * 4);
    int* ecnt      = (int*)alloc((size_t)GG * 4);
    int* deg       = (int*)alloc((size_t)NN * 4);
    int* rowstart  = (int*)alloc((size_t)(NN + 1) * 4);
    unsigned short* perm = (unsigned short*)alloc((size_t)EE * 2);
    unsigned short* cols = (unsigned short*)alloc((size_t)EE * 2);
    int* lists     = (int*)alloc((size_t)NEXP * NN * 4);
    int* cnt8      = (int*)alloc((size_t)NEXP * 4);
    int* order     = (int*)alloc((size_t)NN * 4);
    int* dh        = (int*)alloc((size_t)DBIN * 4);
    int* dcur      = (int*)alloc((size_t)DBIN * 4);

    // expert z-buffers fill the rest of the workspace; group size adapts to ws_size.
    const long BUFS = MPAD * KD;                 // elements per expert buffer
    long avail = ((long)ws_size - (long)off) / (BUFS * 2);
    int EG = (avail < 1) ? 1 : (avail > NEXP ? NEXP : (int)avail);
    unsigned short* bufs = (unsigned short*)(ws + off);

    hipMemsetAsync(ecnt, 0, GG * 4, stream);
    hipMemsetAsync(deg, 0, (size_t)NN * 4, stream);
    hipMemsetAsync(cnt8, 0, NEXP * 4, stream);
    hipMemsetAsync(dh, 0, DBIN * 4, stream);

    pack_experts<<<NEXP * LAY * KD * HH / 256, 256, 0, stream>>>(W_self, W_neigh, BtE);
    pack_ws1<<<HH * HH / 256, 256, 0, stream>>>(Ws1, Bt1);
    encoder_kernel<<<NN, HH, 0, stream>>>(x, W_enc, b_enc, Ash);

    degp_kernel<<<(EE + 255) / 256, 256, 0, stream>>>(dst, deg, perm);
    hist2_kernel<<<HBLK, 256, 0, stream>>>(src, batch, ecnt);
    scan_kernel<<<1, 1024, 0, stream>>>(deg, rowstart);
    scatter2_kernel<<<(EE + 255) / 256, 256, 0, stream>>>(src, dst, perm, rowstart, cols);
    dhist_kernel<<<(NN + 255) / 256, 256, 0, stream>>>(deg, dh);
    dscan_kernel<<<1, 64, 0, stream>>>(dh, dcur);
    dorder_kernel<<<(NN + 255) / 256, 256, 0, stream>>>(deg, dcur, order);
    stru_kernel<<<GG, HH, 0, stream>>>(batch, ecnt, Wt1, bt1, Wt2, bt2, strug);

    // semantic router hidden: T = relu(h @ Ws1 + bs1)
    gemm_kernel<0><<<dim3(GB, 1), 256, 0, stream>>>(Ash, 0, KD, HH, Bt1, 0, bs1, 0,
                                                    Tbuf, 0, HH, nullptr, 0, nullptr, nullptr);
    route_kernel<<<(NN + 3) / 4, 256, 0, stream>>>(Tbuf, Ws2, bs2, strug, batch, sparse, topi);
    build_lists<<<(NN + 255) / 256, 256, 0, stream>>>(sparse, topi, order, cnt8, lists);

    // shared layer-0 aggregation (degree-sorted): Ash[:,256:512] = A . h
    agg_kernel<<<dim3(AGB, 1), 256, 0, stream>>>(Ash, 0, rowstart, cols, order, 0L, nullptr);

    const long BTL = (long)LAY * HH * KD;
    for (int e0 = 0; e0 < NEXP; e0 += EG) {
        int eg = (NEXP - e0 < EG) ? (NEXP - e0) : EG;
        dim3 gg(GB, eg), ga(AGB, eg);
        // layer 0: z1 = relu([h|agg0] @ B0) -> bufs cols 0:255
        gemm_kernel<0><<<gg, 256, 0, stream>>>(Ash, 0, KD, KD,
                                               BtE + (size_t)(e0 * LAY + 0) * HH * KD, BTL,
                                               b_exp + (size_t)e0 * LAY * HH, LAY * HH,
                                               bufs, BUFS, KD, nullptr, 0, nullptr, nullptr);
        agg_kernel<<<ga, 256, 0, stream>>>(bufs, BUFS, rowstart, cols, order, 0L, nullptr);
        // layer 1 IN-PLACE: z2 overwrites z1 cols 0:255 (tile rows fully read before epilogue)
        gemm_kernel<0><<<gg, 256, 0, stream>>>(bufs, BUFS, KD, KD,
                                               BtE + (size_t)(e0 * LAY + 1) * HH * KD, BTL,
                                               b_exp + (size_t)e0 * LAY * HH + HH, LAY * HH,
                                               bufs, BUFS, KD, nullptr, 0, nullptr, nullptr);
        agg_kernel<<<ga, 256, 0, stream>>>(bufs, BUFS, rowstart, cols,
                                           lists + (size_t)e0 * NN, (long)NN, cnt8 + e0);
        // layer 2 on selected rows -> rank-disjoint outR (race-free across experts)
        gemm_kernel<1><<<gg, 256, 0, stream>>>(bufs, BUFS, KD, KD,
                                               BtE + (size_t)(e0 * LAY + 2) * HH * KD, BTL,
                                               b_exp + (size_t)e0 * LAY * HH + 2 * HH, LAY * HH,
                                               outR, 0, 0, sparse, e0,
                                               lists + (size_t)e0 * NN, cnt8 + e0);
    }
    combine_kernel<<<NN * HH / 8 / 256, 256, 0, stream>>>(outR, out);
}

// Round 6
// 2348.051 us; speedup vs baseline: 1.0112x; 1.0112x over previous
//
#include <hip/hip_runtime.h>

// GraphMoE dual router: encoder -> routers -> 8 GraphConv experts (3 layers) -> sparse combine.
// R1: agg latency fix: half-wave/node, 16B/lane, 8 row-gathers in flight.
// R2/R3: ushort cols, top-2 sparsity on layer-2.
// R4: 1-atomic CSR (perm), atomic-free scatter, gll16+XOR-swizzle GEMM, rank-disjoint outR. 2168us.
// R5 FAILED (2378): role-fused gemm||agg — GEMM footprint caps agg occupancy.
// R6 FAILED (2597): agg column-slicing: 64B gathers destroyed L2 reuse (FETCH 687->808MB).
// R7 FAILED (2245): 16-deep unroll + masked tail: VGPR 40->64, occ 57->39%. ILP lever dead.
// R8 FAILED (2374): degree-sorted node order: occ 57->60 only (imbalance theory wrong), agg
//   199->211, FETCH 687->704. LESSON: FETCH responds to row-visit ORDER -> locality lever real.
// R9 (this round): SYNCHRONIZED SOURCE SWEEP. Sort each CSR row's cols ascending (1 thread/
//   node insertion sort; a 32-edge row = one 64B line, ~40us once). All co-resident nodes
//   then walk src low->high together: instantaneous gather window ~1-3MB << 25.6MB, fits
//   per-XCD 4MB L2 -> L3/HBM round-trips become L2 hits. Row gathers stay 512B (R6's mistake
//   avoided). Predict: full agg FETCH 687->~400MB, dur 199->~140us; total ~1850.
//   Falsifier: FETCH unchanged => agg at latency floor; next lever = fp8 gather or roofline.

#define NN 50000
#define EE 1600000
#define GG 64
#define HH 256
#define NEXP 8
#define LAY 3
#define KD 512          // concat K = [z | agg]
#define MT 128          // GEMM row tile per block
#define BK 64           // GEMM K tile
#define GB 391          // (NN + MT - 1) / MT
#define AGB 6250        // NN / 8 agg blocks (8 half-waves each)
#define MPAD 50048L     // 391 * 128

typedef __attribute__((ext_vector_type(8))) short bf16x8;
typedef __attribute__((ext_vector_type(8))) unsigned short u16x8;
typedef __attribute__((ext_vector_type(4))) float f32x4;

__device__ __forceinline__ float bf2f(unsigned short u) {
    union { unsigned int i; float f; } v; v.i = ((unsigned int)u) << 16; return v.f;
}
__device__ __forceinline__ unsigned short f2bf(float f) {
    union { unsigned int i; float f; } v; v.f = f;
    unsigned int r = (v.i + 0x7FFFu + ((v.i >> 16) & 1u)) >> 16;
    return (unsigned short)r;
}
__device__ __forceinline__ void gll16(unsigned short* l, const unsigned short* g) {
    __builtin_amdgcn_global_load_lds((__attribute__((address_space(1))) void*)g,
                                     (__attribute__((address_space(3))) void*)l, 16, 0, 0);
}

// ---------------- encoder: h = relu(x[:,4:10] @ W_enc + b_enc), bf16 into Ash cols 0..255
__global__ void encoder_kernel(const float* __restrict__ x, const float* __restrict__ W,
                               const float* __restrict__ b, unsigned short* __restrict__ out) {
    int n = blockIdx.x, j = threadIdx.x;
    float acc = b[j];
#pragma unroll
    for (int i = 0; i < 6; i++) acc += x[n * 10 + 4 + i] * W[i * HH + j];
    acc = fmaxf(acc, 0.f);
    out[(long)n * KD + j] = f2bf(acc);
}

// ---------------- weight packing: Bt[(e*3+l)][n][k] bf16, k<256 -> W_self, k>=256 -> W_neigh
__global__ void pack_experts(const float* __restrict__ Wself, const float* __restrict__ Wneigh,
                             unsigned short* __restrict__ Bt) {
    int idx = blockIdx.x * 256 + threadIdx.x;          // (e,l,k,n), n fastest
    int n = idx & 255; int r = idx >> 8;
    int k = r & 511; r >>= 9;
    int l = r % LAY; int e = r / LAY;
    float v = (k < 256) ? Wself[(((e * LAY + l) * HH) + k) * HH + n]
                        : Wneigh[(((e * LAY + l) * HH) + (k - 256)) * HH + n];
    Bt[(((long)(e * LAY + l) * HH + n) * KD) + k] = f2bf(v);
}

__global__ void pack_ws1(const float* __restrict__ W, unsigned short* __restrict__ Bt) {
    int idx = blockIdx.x * 256 + threadIdx.x;
    int n = idx & 255; int k = idx >> 8;
    Bt[(long)n * HH + k] = f2bf(W[k * HH + n]);
}

// ---------------- degree pass: ONE atomic per edge; returned old value = within-row slot.
__global__ void degp_kernel(const int* __restrict__ dst, int* __restrict__ deg,
                            unsigned short* __restrict__ perm) {
    int e = blockIdx.x * 256 + threadIdx.x;
    if (e < EE) perm[e] = (unsigned short)atomicAdd(&deg[dst[e]], 1);  // max in-degree << 65536
}

// ---------------- per-graph edge histogram via ballot: 1 ballot/edge, no per-edge atomics.
#define HBLK 128
#define HITER ((EE + HBLK * 256 - 1) / (HBLK * 256))
__global__ void hist2_kernel(const int* __restrict__ src, const int* __restrict__ batch,
                             int* __restrict__ ecnt) {
    __shared__ int h[GG];
    if (threadIdx.x < GG) h[threadIdx.x] = 0;
    __syncthreads();
    int lane = threadIdx.x & 63;
    int gid = blockIdx.x * 256 + threadIdx.x;
    int cnt = 0;
    for (int it = 0; it < HITER; it++) {
        long e = (long)it * (HBLK * 256) + gid;
        int g = (e < EE) ? batch[src[e]] : -1;
        for (int gg = 0; gg < GG; gg++) {
            unsigned long long m = __ballot(g == gg);
            if (lane == gg) cnt += (int)__popcll(m);
        }
    }
    atomicAdd(&h[lane], cnt);
    __syncthreads();
    if (threadIdx.x < GG && h[threadIdx.x]) atomicAdd(&ecnt[threadIdx.x], h[threadIdx.x]);
}

// ---------------- structural router per graph; node count via binary search on sorted batch
__global__ void stru_kernel(const int* __restrict__ batch, const int* __restrict__ ecnt,
                            const float* __restrict__ Wt1, const float* __restrict__ bt1,
                            const float* __restrict__ Wt2, const float* __restrict__ bt2,
                            float* __restrict__ strug) {
    __shared__ float t[HH];
    __shared__ int nc;
    int g = blockIdx.x, j = threadIdx.x;
    if (j == 0) {
        int lo = 0, hi = NN;
        while (lo < hi) { int mid = (lo + hi) >> 1; if (batch[mid] < g) lo = mid + 1; else hi = mid; }
        int s = lo; lo = 0; hi = NN;
        while (lo < hi) { int mid = (lo + hi) >> 1; if (batch[mid] < g + 1) lo = mid + 1; else hi = mid; }
        nc = lo - s;
    }
    __syncthreads();
    float nf = log1pf((float)nc);
    float ef = log1pf((float)ecnt[g]);
    float v = nf * Wt1[j] + ef * Wt1[HH + j] + bt1[j];
    t[j] = fmaxf(v, 0.f);
    __syncthreads();
    if (j < 8) {
        float sum = bt2[j];
        for (int k = 0; k < HH; k++) sum += t[k] * Wt2[k * 8 + j];
        strug[g * 8 + j] = sum;
    }
}

// single block, 1024 threads; shuffle-based inclusive scan
__global__ void scan_kernel(const int* __restrict__ deg, int* __restrict__ rowstart) {
    __shared__ int wsum[16];
    __shared__ int carry_s;
    int tid = threadIdx.x;
    int wid = tid >> 6, lane = tid & 63;
    if (tid == 0) carry_s = 0;
    __syncthreads();
    for (int base = 0; base < NN; base += 1024) {
        int i = base + tid;
        int v = (i < NN) ? deg[i] : 0;
        int sc = v;
#pragma unroll
        for (int off = 1; off < 64; off <<= 1) {
            int t = __shfl_up(sc, off, 64);
            if (lane >= off) sc += t;
        }
        if (lane == 63) wsum[wid] = sc;
        __syncthreads();
        int carry = carry_s;
        int prev = 0;
        for (int w = 0; w < wid; w++) prev += wsum[w];
        int excl = carry + prev + sc - v;
        if (i < NN) rowstart[i] = excl;
        __syncthreads();
        if (tid == 1023) carry_s = carry + prev + sc;
    }
    __syncthreads();
    if (tid == 0) rowstart[NN] = carry_s;
}

// ---------------- atomic-free scatter: position = rowstart[dst] + perm
__global__ void scatter2_kernel(const int* __restrict__ src, const int* __restrict__ dst,
                                const unsigned short* __restrict__ perm,
                                const int* __restrict__ rowstart,
                                unsigned short* __restrict__ cols) {
    int e = blockIdx.x * 256 + threadIdx.x;
    if (e < EE) cols[rowstart[dst[e]] + (int)perm[e]] = (unsigned short)src[e];
}

// ---------------- per-row src sort: 1 thread/node insertion sort. A ~32-edge row is one
// 64B cache line; serial but L1-resident. Enables the synchronized low->high src sweep.
__global__ void sortrow_kernel(const int* __restrict__ rowstart, unsigned short* __restrict__ cols) {
    int n = blockIdx.x * 256 + threadIdx.x;
    if (n >= NN) return;
    int s = rowstart[n], e = rowstart[n + 1];
    for (int i = s + 1; i < e; i++) {
        unsigned short key = cols[i];
        int j = i - 1;
        while (j >= s && cols[j] > key) { cols[j + 1] = cols[j]; j--; }
        cols[j + 1] = key;
    }
}

// ---------------- aggregation (R4 form): Z[nid,256:512] = sum_{in-nb} Z[src,0:256]
// half-wave (32 lanes) per node, 16B/lane (512B/row-gather), unroll x8 -> 8 row-gathers
// in flight. Rows walk src ascending (sorted cols) -> cohort-synchronized sweep.
__global__ void agg_kernel(unsigned short* __restrict__ base, long estride,
                           const int* __restrict__ rowstart, const unsigned short* __restrict__ cols,
                           const int* __restrict__ listp, const int* __restrict__ cntp) {
    unsigned short* Z = base + (long)blockIdx.y * estride;
    int half = threadIdx.x >> 5;               // 0..7
    int lane = threadIdx.x & 31;
    int idx = blockIdx.x * 8 + half;
    int limit = cntp ? cntp[blockIdx.y] : NN;
    if (idx >= limit) return;                  // half-wave uniform
    int nid = listp ? (listp[(long)blockIdx.y * NN + idx] & 0xFFFF) : idx;
    int s = rowstart[nid], e = rowstart[nid + 1];
    float acc[8] = {0.f, 0.f, 0.f, 0.f, 0.f, 0.f, 0.f, 0.f};
    int i = s;
    for (; i + 8 <= e; i += 8) {
        int c[8];
#pragma unroll
        for (int u = 0; u < 8; u++) c[u] = (int)cols[i + u];
        u16x8 v[8];
#pragma unroll
        for (int u = 0; u < 8; u++) v[u] = *(const u16x8*)&Z[(long)c[u] * KD + lane * 8];
#pragma unroll
        for (int u = 0; u < 8; u++)
#pragma unroll
            for (int j = 0; j < 8; j++) acc[j] += bf2f(v[u][j]);
    }
    for (; i < e; i++) {
        int c = (int)cols[i];
        u16x8 v = *(const u16x8*)&Z[(long)c * KD + lane * 8];
#pragma unroll
        for (int j = 0; j < 8; j++) acc[j] += bf2f(v[j]);
    }
    u16x8 o;
#pragma unroll
    for (int j = 0; j < 8; j++) o[j] = f2bf(acc[j]);
    *(u16x8*)&Z[(long)nid * KD + 256 + lane * 8] = o;
}

// ---------------- semantic router tail + softmax + top-2 + renormalize (wave per node)
__global__ void route_kernel(const unsigned short* __restrict__ T, const float* __restrict__ Ws2,
                             const float* __restrict__ bs2, const float* __restrict__ strug,
                             const int* __restrict__ batch, float* __restrict__ sparse,
                             int* __restrict__ topi) {
    int nid = blockIdx.x * 4 + (threadIdx.x >> 6);
    if (nid >= NN) return;
    int lane = threadIdx.x & 63;
    float s[8];
#pragma unroll
    for (int j = 0; j < 8; j++) s[j] = 0.f;
    ushort4 t4 = *(const ushort4*)&T[(long)nid * HH + lane * 4];
    float tv[4] = { bf2f(t4.x), bf2f(t4.y), bf2f(t4.z), bf2f(t4.w) };
#pragma unroll
    for (int kk = 0; kk < 4; kk++) {
        int k = lane * 4 + kk;
#pragma unroll
        for (int j = 0; j < 8; j++) s[j] += tv[kk] * Ws2[k * 8 + j];
    }
#pragma unroll
    for (int off = 32; off >= 1; off >>= 1) {
#pragma unroll
        for (int j = 0; j < 8; j++) s[j] += __shfl_xor(s[j], off, 64);
    }
    int g = batch[nid];
    float p[8], mx = -1e30f;
#pragma unroll
    for (int j = 0; j < 8; j++) {
        p[j] = 0.5f * (s[j] + bs2[j] + strug[g * 8 + j]);
        mx = fmaxf(mx, p[j]);
    }
    float ex[8];
#pragma unroll
    for (int j = 0; j < 8; j++) ex[j] = expf(p[j] - mx);
    int i1 = 0;
#pragma unroll
    for (int j = 1; j < 8; j++) if (ex[j] > ex[i1]) i1 = j;
    int i2 = (i1 == 0) ? 1 : 0;
#pragma unroll
    for (int j = 0; j < 8; j++) if (j != i1 && ex[j] > ex[i2]) i2 = j;
    float r = 1.f / (ex[i1] + ex[i2]);
    if (lane == 0) topi[nid] = i1 | (i2 << 8);
    if (lane < 8)
        sparse[(long)nid * 8 + lane] = (lane == i1) ? ex[i1] * r : (lane == i2) ? ex[i2] * r : 0.f;
}

// ---------------- per-expert selected-node lists; entries packed n | rank<<16
__global__ void build_lists(const float* __restrict__ sparse, const int* __restrict__ topi,
                            int* __restrict__ cnt, int* __restrict__ lists) {
    __shared__ int lc[NEXP], lb[NEXP];
    int tid = threadIdx.x;
    if (tid < NEXP) lc[tid] = 0;
    __syncthreads();
    int n = blockIdx.x * 256 + tid;
    int le_[2], pk_[2], ps_[2];
    int cc = 0;
    if (n < NN) {
        int t1 = topi[n] & 0xFF;
#pragma unroll
        for (int e = 0; e < NEXP; e++) {
            if (sparse[(long)n * 8 + e] > 0.f && cc < 2) {
                le_[cc] = e;
                pk_[cc] = n | ((e == t1) ? 0 : (1 << 16));
                ps_[cc] = atomicAdd(&lc[e], 1);
                cc++;
            }
        }
    }
    __syncthreads();
    if (tid < NEXP) lb[tid] = atomicAdd(&cnt[tid], lc[tid]);
    __syncthreads();
    for (int c = 0; c < cc; c++)
        lists[(long)le_[c] * NN + lb[le_[c]] + ps_[c]] = pk_[c];
}

// ---------------- MFMA GEMM: C[M,256] = A[M,K]_bf16 @ Bt[256,K]_bf16 (+bias)
// blockIdx.y = expert slot. gll16 staging, linear LDS + chunk^(row&7) XOR swizzle.
// MODE 0: relu, store bf16 (stride ldz). MODE 1: rows from packed list; store
// w * (acc+bias) bf16 into rank-disjoint outR planes.
template <int MODE>
__global__ __launch_bounds__(256, 2) void gemm_kernel(
    const unsigned short* __restrict__ A, long ae, int lda, int K,
    const unsigned short* __restrict__ Bt, long bte,
    const float* __restrict__ bias, int be_s,
    void* __restrict__ outp, long oe, int ldz,
    const float* __restrict__ sparse, int e0,
    const int* __restrict__ listp, const int* __restrict__ cntp) {
    __shared__ __align__(16) unsigned short Alds[MT * 64];
    __shared__ __align__(16) unsigned short Blds[HH * 64];
    __shared__ int nodeids[MT];
    const int el = blockIdx.y;
    const unsigned short* Ae = A + (long)el * ae;
    const unsigned short* Bte = Bt + (long)el * bte;
    const float* be = bias + (long)el * be_s;
    const int tid = threadIdx.x;
    const int wave = tid >> 6, lane = tid & 63;
    const int m = lane & 15, q = lane >> 4;
    const long row0 = (long)blockIdx.x * MT;

    if constexpr (MODE == 1) {
        int limit = cntp[el];
        if (row0 >= limit) return;              // uniform exit
        if (tid < MT) {
            long rr = row0 + tid;
            nodeids[tid] = (rr < limit) ? listp[(long)el * NN + rr] : -1;
        }
        __syncthreads();
    }

    const unsigned short* asrc[4];
#pragma unroll
    for (int i = 0; i < 4; i++) {
        int slot = tid + 256 * i;
        int r = slot >> 3, cg = (slot & 7) ^ (r & 7);
        long arow;
        if constexpr (MODE == 0) {
            arow = row0 + r;                    // padded rows < MPAD: garbage, masked on store
        } else {
            int v = nodeids[r];
            arow = (v >= 0) ? (v & 0xFFFF) : 0;
        }
        asrc[i] = Ae + arow * (long)lda + cg * 8;
    }
    const unsigned short* bsrc[8];
#pragma unroll
    for (int i = 0; i < 8; i++) {
        int slot = tid + 256 * i;
        int r = slot >> 3, cg = (slot & 7) ^ (r & 7);
        bsrc[i] = Bte + (long)r * K + cg * 8;
    }

    f32x4 acc[2][16];
#pragma unroll
    for (int i = 0; i < 2; i++)
#pragma unroll
        for (int j = 0; j < 16; j++) acc[i][j] = (f32x4){0.f, 0.f, 0.f, 0.f};

    const int swz = (m & 7) << 3;
    for (int k0 = 0; k0 < K; k0 += BK) {
#pragma unroll
        for (int i = 0; i < 4; i++) gll16(&Alds[(tid + 256 * i) * 8], asrc[i] + k0);
#pragma unroll
        for (int i = 0; i < 8; i++) gll16(&Blds[(tid + 256 * i) * 8], bsrc[i] + k0);
        __syncthreads();
#pragma unroll
        for (int kk = 0; kk < BK; kk += 32) {
            const int ch8 = (((kk >> 3) + q) << 3) ^ swz;
            const int ao = (wave * 32 + m) * 64 + ch8;
            bf16x8 a0 = *(const bf16x8*)&Alds[ao];
            bf16x8 a1 = *(const bf16x8*)&Alds[ao + 16 * 64];
#pragma unroll
            for (int ct = 0; ct < 16; ct++) {
                bf16x8 b = *(const bf16x8*)&Blds[(ct * 16 + m) * 64 + ch8];
                acc[0][ct] = __builtin_amdgcn_mfma_f32_16x16x32_bf16(a0, b, acc[0][ct], 0, 0, 0);
                acc[1][ct] = __builtin_amdgcn_mfma_f32_16x16x32_bf16(a1, b, acc[1][ct], 0, 0, 0);
            }
        }
        __syncthreads();
    }
    // epilogue: D layout col = lane&15, row = (lane>>4)*4 + reg
#pragma unroll
    for (int mt = 0; mt < 2; mt++) {
        int rtile = wave * 32 + mt * 16 + q * 4;
        if constexpr (MODE == 0) {
            unsigned short* oute = (unsigned short*)outp + (long)el * oe;
            long rbase = row0 + rtile;
#pragma unroll
            for (int ct = 0; ct < 16; ct++) {
                int col = ct * 16 + m;
                float bv = be[col];
#pragma unroll
                for (int r = 0; r < 4; r++) {
                    long grow = rbase + r;
                    if (grow < NN) {
                        float v = fmaxf(acc[mt][ct][r] + bv, 0.f);
                        oute[grow * ldz + col] = f2bf(v);
                    }
                }
            }
        } else {
            unsigned short* outR = (unsigned short*)outp;
            int v4[4]; float w4[4];
#pragma unroll
            for (int r = 0; r < 4; r++) {
                v4[r] = nodeids[rtile + r];
                w4[r] = (v4[r] >= 0) ? sparse[(long)(v4[r] & 0xFFFF) * 8 + e0 + el] : 0.f;
            }
#pragma unroll
            for (int ct = 0; ct < 16; ct++) {
                int col = ct * 16 + m;
                float bv = be[col];
#pragma unroll
                for (int r = 0; r < 4; r++) {
                    if (v4[r] >= 0) {
                        long nid = v4[r] & 0xFFFF;
                        long rank = (v4[r] >> 16) & 1;
                        outR[(rank * MPAD + nid) * HH + col] = f2bf(w4[r] * (acc[mt][ct][r] + bv));
                    }
                }
            }
        }
    }
}

// ---------------- final combine: out = rank0 + rank1 (weights already applied)
__global__ void combine_kernel(const unsigned short* __restrict__ outR, float* __restrict__ out) {
    long base = ((long)blockIdx.x * 256 + threadIdx.x) * 8;
    u16x8 r0 = *(const u16x8*)&outR[base];
    u16x8 r1 = *(const u16x8*)&outR[MPAD * HH + base];
    f32x4 lo, hi;
#pragma unroll
    for (int j = 0; j < 4; j++) lo[j] = bf2f(r0[j]) + bf2f(r1[j]);
#pragma unroll
    for (int j = 0; j < 4; j++) hi[j] = bf2f(r0[j + 4]) + bf2f(r1[j + 4]);
    *(f32x4*)&out[base] = lo;
    *(f32x4*)&out[base + 4] = hi;
}

extern "C" void kernel_launch(void* const* d_in, const int* in_sizes, int n_in,
                              void* d_out, int out_size, void* d_ws, size_t ws_size,
                              hipStream_t stream) {
    const float* x     = (const float*)d_in[0];
    const int*   ei    = (const int*)d_in[1];
    const int*   src   = ei;
    const int*   dst   = ei + EE;
    const int*   batch = (const int*)d_in[2];
    const float* W_enc = (const float*)d_in[3];
    const float* b_enc = (const float*)d_in[4];
    const float* Ws1   = (const float*)d_in[5];
    const float* bs1   = (const float*)d_in[6];
    const float* Ws2   = (const float*)d_in[7];
    const float* bs2   = (const float*)d_in[8];
    const float* Wt1   = (const float*)d_in[9];
    const float* bt1   = (const float*)d_in[10];
    const float* Wt2   = (const float*)d_in[11];
    const float* bt2   = (const float*)d_in[12];
    const float* W_self  = (const float*)d_in[13];
    const float* W_neigh = (const float*)d_in[14];
    const float* b_exp   = (const float*)d_in[15];
    float* out = (float*)d_out;

    char* ws = (char*)d_ws;
    size_t off = 0;
    auto alloc = [&](size_t b) { size_t p = off; off = (off + b + 255) & ~(size_t)255; return ws + p; };

    unsigned short* Ash  = (unsigned short*)alloc((size_t)MPAD * KD * 2);
    unsigned short* outR = (unsigned short*)alloc((size_t)2 * MPAD * HH * 2);
    unsigned short* Tbuf = outR;  // alias: router hidden consumed before outR first written
    unsigned short* BtE = (unsigned short*)alloc((size_t)NEXP * LAY * HH * KD * 2);
    unsigned short* Bt1 = (unsigned short*)alloc((size_t)HH * HH * 2);
    float* sparse  = (float*)alloc((size_t)NN * 8 * 4);
    int* topi      = (int*)alloc((size_t)NN * 4);
    float* strug   = (float*)alloc((size_t)GG * 8 * 4);
    int* ecnt      = (int*)alloc((size_t)GG * 4);
    int* deg       = (int*)alloc((size_t)NN * 4);
    int* rowstart  = (int*)alloc((size_t)(NN + 1) * 4);
    unsigned short* perm = (unsigned short*)alloc((size_t)EE * 2);
    unsigned short* cols = (unsigned short*)alloc((size_t)EE * 2);
    int* lists     = (int*)alloc((size_t)NEXP * NN * 4);
    int* cnt8      = (int*)alloc((size_t)NEXP * 4);

    // expert z-buffers fill the rest of the workspace; group size adapts to ws_size.
    const long BUFS = MPAD * KD;                 // elements per expert buffer
    long avail = ((long)ws_size - (long)off) / (BUFS * 2);
    int EG = (avail < 1) ? 1 : (avail > NEXP ? NEXP : (int)avail);
    unsigned short* bufs = (unsigned short*)(ws + off);

    hipMemsetAsync(ecnt, 0, GG * 4, stream);
    hipMemsetAsync(deg, 0, (size_t)NN * 4, stream);
    hipMemsetAsync(cnt8, 0, NEXP * 4, stream);

    pack_experts<<<NEXP * LAY * KD * HH / 256, 256, 0, stream>>>(W_self, W_neigh, BtE);
    pack_ws1<<<HH * HH / 256, 256, 0, stream>>>(Ws1, Bt1);
    encoder_kernel<<<NN, HH, 0, stream>>>(x, W_enc, b_enc, Ash);

    degp_kernel<<<(EE + 255) / 256, 256, 0, stream>>>(dst, deg, perm);
    hist2_kernel<<<HBLK, 256, 0, stream>>>(src, batch, ecnt);
    scan_kernel<<<1, 1024, 0, stream>>>(deg, rowstart);
    scatter2_kernel<<<(EE + 255) / 256, 256, 0, stream>>>(src, dst, perm, rowstart, cols);
    sortrow_kernel<<<(NN + 255) / 256, 256, 0, stream>>>(rowstart, cols);
    stru_kernel<<<GG, HH, 0, stream>>>(batch, ecnt, Wt1, bt1, Wt2, bt2, strug);

    // semantic router hidden: T = relu(h @ Ws1 + bs1)
    gemm_kernel<0><<<dim3(GB, 1), 256, 0, stream>>>(Ash, 0, KD, HH, Bt1, 0, bs1, 0,
                                                    Tbuf, 0, HH, nullptr, 0, nullptr, nullptr);
    route_kernel<<<(NN + 3) / 4, 256, 0, stream>>>(Tbuf, Ws2, bs2, strug, batch, sparse, topi);
    build_lists<<<(NN + 255) / 256, 256, 0, stream>>>(sparse, topi, cnt8, lists);

    // shared layer-0 aggregation: Ash[:,256:512] = A . h  (reused by all 8 experts)
    agg_kernel<<<dim3(AGB, 1), 256, 0, stream>>>(Ash, 0, rowstart, cols, nullptr, nullptr);

    const long BTL = (long)LAY * HH * KD;
    for (int e0 = 0; e0 < NEXP; e0 += EG) {
        int eg = (NEXP - e0 < EG) ? (NEXP - e0) : EG;
        dim3 gg(GB, eg), ga(AGB, eg);
        // layer 0: z1 = relu([h|agg0] @ B0) -> bufs cols 0:255
        gemm_kernel<0><<<gg, 256, 0, stream>>>(Ash, 0, KD, KD,
                                               BtE + (size_t)(e0 * LAY + 0) * HH * KD, BTL,
                                               b_exp + (size_t)e0 * LAY * HH, LAY * HH,
                                               bufs, BUFS, KD, nullptr, 0, nullptr, nullptr);
        agg_kernel<<<ga, 256, 0, stream>>>(bufs, BUFS, rowstart, cols, nullptr, nullptr);
        // layer 1 IN-PLACE: z2 overwrites z1 cols 0:255 (tile rows fully read before epilogue)
        gemm_kernel<0><<<gg, 256, 0, stream>>>(bufs, BUFS, KD, KD,
                                               BtE + (size_t)(e0 * LAY + 1) * HH * KD, BTL,
                                               b_exp + (size_t)e0 * LAY * HH + HH, LAY * HH,
                                               bufs, BUFS, KD, nullptr, 0, nullptr, nullptr);
        agg_kernel<<<ga, 256, 0, stream>>>(bufs, BUFS, rowstart, cols,
                                           lists + (size_t)e0 * NN, cnt8 + e0);
        // layer 2 on selected rows -> rank-disjoint outR (race-free across experts)
        gemm_kernel<1><<<gg, 256, 0, stream>>>(bufs, BUFS, KD, KD,
                                               BtE + (size_t)(e0 * LAY + 2) * HH * KD, BTL,
                                               b_exp + (size_t)e0 * LAY * HH + 2 * HH, LAY * HH,
                                               outR, 0, 0, sparse, e0,
                                               lists + (size_t)e0 * NN, cnt8 + e0);
    }
    combine_kernel<<<NN * HH / 8 / 256, 256, 0, stream>>>(outR, out);
}

// Round 7
// 2152.133 us; speedup vs baseline: 1.1033x; 1.0910x over previous
//
#include <hip/hip_runtime.h>

// GraphMoE dual router: encoder -> routers -> 8 GraphConv experts (3 layers) -> sparse combine.
// R1: agg latency fix: half-wave/node, 16B/lane, 8 row-gathers in flight.
// R2/R3: ushort cols, top-2 sparsity on layer-2.
// R4: 1-atomic CSR (perm), atomic-free scatter, gll16+XOR-swizzle GEMM, rank-disjoint outR. 2168us.
// R5 FAILED (2378): role-fused gemm||agg — GEMM footprint caps agg occupancy.
// R6 FAILED (2597): agg column-slicing: 64B gathers destroyed L2 reuse.
// R7 FAILED (2245): 16-deep unroll: VGPR 40->64, occ 57->39%. ILP lever dead.
// R8 FAILED (2374): degree-sorted node order: occupancy theory wrong; FETCH order-sensitive.
// R9 MIXED (2348): sorted-cols sweep: agg gained ~56us (locality lever real) but serial
//   insertion sortrow cost 236us (occ 7%, VALU 2.7% — latency chain). Keep sweep, fix sort.
// R10 (this round): half-wave BITONIC sort in registers: 32 lanes x 4 vals = 128-slot
//   network, __shfl_xor(w=32) for dist<32, reg-slot cmpex for dist>=32, 0xFFFF pad,
//   serial fallback d>128 (Poisson(32): never). ~350 VALU ops/node ~ 10-15us total.
//   Predict: psort ~15us @ VALU>60%, aggs unchanged from R9, total ~2120.
//   Next lever if this lands: GEMM 2-phase prefetch (~560us at ~440TF, documented headroom).

#define NN 50000
#define EE 1600000
#define GG 64
#define HH 256
#define NEXP 8
#define LAY 3
#define KD 512          // concat K = [z | agg]
#define MT 128          // GEMM row tile per block
#define BK 64           // GEMM K tile
#define GB 391          // (NN + MT - 1) / MT
#define AGB 6250        // NN / 8 agg blocks (8 half-waves each)
#define MPAD 50048L     // 391 * 128

typedef __attribute__((ext_vector_type(8))) short bf16x8;
typedef __attribute__((ext_vector_type(8))) unsigned short u16x8;
typedef __attribute__((ext_vector_type(4))) float f32x4;

__device__ __forceinline__ float bf2f(unsigned short u) {
    union { unsigned int i; float f; } v; v.i = ((unsigned int)u) << 16; return v.f;
}
__device__ __forceinline__ unsigned short f2bf(float f) {
    union { unsigned int i; float f; } v; v.f = f;
    unsigned int r = (v.i + 0x7FFFu + ((v.i >> 16) & 1u)) >> 16;
    return (unsigned short)r;
}
__device__ __forceinline__ void gll16(unsigned short* l, const unsigned short* g) {
    __builtin_amdgcn_global_load_lds((__attribute__((address_space(1))) void*)g,
                                     (__attribute__((address_space(3))) void*)l, 16, 0, 0);
}

// ---------------- encoder: h = relu(x[:,4:10] @ W_enc + b_enc), bf16 into Ash cols 0..255
__global__ void encoder_kernel(const float* __restrict__ x, const float* __restrict__ W,
                               const float* __restrict__ b, unsigned short* __restrict__ out) {
    int n = blockIdx.x, j = threadIdx.x;
    float acc = b[j];
#pragma unroll
    for (int i = 0; i < 6; i++) acc += x[n * 10 + 4 + i] * W[i * HH + j];
    acc = fmaxf(acc, 0.f);
    out[(long)n * KD + j] = f2bf(acc);
}

// ---------------- weight packing: Bt[(e*3+l)][n][k] bf16, k<256 -> W_self, k>=256 -> W_neigh
__global__ void pack_experts(const float* __restrict__ Wself, const float* __restrict__ Wneigh,
                             unsigned short* __restrict__ Bt) {
    int idx = blockIdx.x * 256 + threadIdx.x;          // (e,l,k,n), n fastest
    int n = idx & 255; int r = idx >> 8;
    int k = r & 511; r >>= 9;
    int l = r % LAY; int e = r / LAY;
    float v = (k < 256) ? Wself[(((e * LAY + l) * HH) + k) * HH + n]
                        : Wneigh[(((e * LAY + l) * HH) + (k - 256)) * HH + n];
    Bt[(((long)(e * LAY + l) * HH + n) * KD) + k] = f2bf(v);
}

__global__ void pack_ws1(const float* __restrict__ W, unsigned short* __restrict__ Bt) {
    int idx = blockIdx.x * 256 + threadIdx.x;
    int n = idx & 255; int k = idx >> 8;
    Bt[(long)n * HH + k] = f2bf(W[k * HH + n]);
}

// ---------------- degree pass: ONE atomic per edge; returned old value = within-row slot.
__global__ void degp_kernel(const int* __restrict__ dst, int* __restrict__ deg,
                            unsigned short* __restrict__ perm) {
    int e = blockIdx.x * 256 + threadIdx.x;
    if (e < EE) perm[e] = (unsigned short)atomicAdd(&deg[dst[e]], 1);  // max in-degree << 65536
}

// ---------------- per-graph edge histogram via ballot: 1 ballot/edge, no per-edge atomics.
#define HBLK 128
#define HITER ((EE + HBLK * 256 - 1) / (HBLK * 256))
__global__ void hist2_kernel(const int* __restrict__ src, const int* __restrict__ batch,
                             int* __restrict__ ecnt) {
    __shared__ int h[GG];
    if (threadIdx.x < GG) h[threadIdx.x] = 0;
    __syncthreads();
    int lane = threadIdx.x & 63;
    int gid = blockIdx.x * 256 + threadIdx.x;
    int cnt = 0;
    for (int it = 0; it < HITER; it++) {
        long e = (long)it * (HBLK * 256) + gid;
        int g = (e < EE) ? batch[src[e]] : -1;
        for (int gg = 0; gg < GG; gg++) {
            unsigned long long m = __ballot(g == gg);
            if (lane == gg) cnt += (int)__popcll(m);
        }
    }
    atomicAdd(&h[lane], cnt);
    __syncthreads();
    if (threadIdx.x < GG && h[threadIdx.x]) atomicAdd(&ecnt[threadIdx.x], h[threadIdx.x]);
}

// ---------------- structural router per graph; node count via binary search on sorted batch
__global__ void stru_kernel(const int* __restrict__ batch, const int* __restrict__ ecnt,
                            const float* __restrict__ Wt1, const float* __restrict__ bt1,
                            const float* __restrict__ Wt2, const float* __restrict__ bt2,
                            float* __restrict__ strug) {
    __shared__ float t[HH];
    __shared__ int nc;
    int g = blockIdx.x, j = threadIdx.x;
    if (j == 0) {
        int lo = 0, hi = NN;
        while (lo < hi) { int mid = (lo + hi) >> 1; if (batch[mid] < g) lo = mid + 1; else hi = mid; }
        int s = lo; lo = 0; hi = NN;
        while (lo < hi) { int mid = (lo + hi) >> 1; if (batch[mid] < g + 1) lo = mid + 1; else hi = mid; }
        nc = lo - s;
    }
    __syncthreads();
    float nf = log1pf((float)nc);
    float ef = log1pf((float)ecnt[g]);
    float v = nf * Wt1[j] + ef * Wt1[HH + j] + bt1[j];
    t[j] = fmaxf(v, 0.f);
    __syncthreads();
    if (j < 8) {
        float sum = bt2[j];
        for (int k = 0; k < HH; k++) sum += t[k] * Wt2[k * 8 + j];
        strug[g * 8 + j] = sum;
    }
}

// single block, 1024 threads; shuffle-based inclusive scan
__global__ void scan_kernel(const int* __restrict__ deg, int* __restrict__ rowstart) {
    __shared__ int wsum[16];
    __shared__ int carry_s;
    int tid = threadIdx.x;
    int wid = tid >> 6, lane = tid & 63;
    if (tid == 0) carry_s = 0;
    __syncthreads();
    for (int base = 0; base < NN; base += 1024) {
        int i = base + tid;
        int v = (i < NN) ? deg[i] : 0;
        int sc = v;
#pragma unroll
        for (int off = 1; off < 64; off <<= 1) {
            int t = __shfl_up(sc, off, 64);
            if (lane >= off) sc += t;
        }
        if (lane == 63) wsum[wid] = sc;
        __syncthreads();
        int carry = carry_s;
        int prev = 0;
        for (int w = 0; w < wid; w++) prev += wsum[w];
        int excl = carry + prev + sc - v;
        if (i < NN) rowstart[i] = excl;
        __syncthreads();
        if (tid == 1023) carry_s = carry + prev + sc;
    }
    __syncthreads();
    if (tid == 0) rowstart[NN] = carry_s;
}

// ---------------- atomic-free scatter: position = rowstart[dst] + perm
__global__ void scatter2_kernel(const int* __restrict__ src, const int* __restrict__ dst,
                                const unsigned short* __restrict__ perm,
                                const int* __restrict__ rowstart,
                                unsigned short* __restrict__ cols) {
    int e = blockIdx.x * 256 + threadIdx.x;
    if (e < EE) cols[rowstart[dst[e]] + (int)perm[e]] = (unsigned short)src[e];
}

// ---------------- per-row src sort, half-wave bitonic: 32 lanes x 4 regs = 128-slot network.
// dist<32 via __shfl_xor(width=32), dist>=32 via register-slot cmpex. Pad 0xFFFF.
// Enables the synchronized low->high src sweep in agg. Serial fallback for d>128 (rare).
__global__ void psort_kernel(const int* __restrict__ rowstart, unsigned short* __restrict__ cols) {
    int half = threadIdx.x >> 5;
    int lane = threadIdx.x & 31;
    int n = blockIdx.x * 8 + half;
    if (n >= NN) return;
    int s = rowstart[n], e = rowstart[n + 1];
    int d = e - s;
    if (d <= 1) return;
    if (d > 128) {                       // safety fallback; Poisson(32) never hits this
        if (lane == 0) {
            for (int i = s + 1; i < e; i++) {
                unsigned short key = cols[i];
                int j = i - 1;
                while (j >= s && cols[j] > key) { cols[j + 1] = cols[j]; j--; }
                cols[j + 1] = key;
            }
        }
        return;
    }
    unsigned int r[4];
#pragma unroll
    for (int i = 0; i < 4; i++) {
        int v = i * 32 + lane;
        r[i] = (v < d) ? (unsigned int)cols[s + v] : 0xFFFFu;
    }
#pragma unroll
    for (int k = 2; k <= 128; k <<= 1) {
#pragma unroll
        for (int j = 64; j > 0; j >>= 1) {
            if (j >= k) continue;        // run stages j = k/2 .. 1
            if (j >= 32) {
                int js = j >> 5;
#pragma unroll
                for (int i = 0; i < 4; i++) {
                    int i2 = i ^ js;
                    if (i < i2) {
                        int v = i * 32 + lane;
                        unsigned int a = r[i], b = r[i2];
                        unsigned int mn = a < b ? a : b, mx = a < b ? b : a;
                        bool up = (v & k) == 0;
                        r[i]  = up ? mn : mx;
                        r[i2] = up ? mx : mn;
                    }
                }
            } else {
#pragma unroll
                for (int i = 0; i < 4; i++) {
                    int v = i * 32 + lane;
                    unsigned int p = (unsigned int)__shfl_xor((int)r[i], j, 32);
                    unsigned int mn = r[i] < p ? r[i] : p, mx = r[i] < p ? p : r[i];
                    bool up = (v & k) == 0;
                    bool lo = (v & j) == 0;
                    r[i] = (up == lo) ? mn : mx;
                }
            }
        }
    }
#pragma unroll
    for (int i = 0; i < 4; i++) {
        int v = i * 32 + lane;
        if (v < d) cols[s + v] = (unsigned short)r[i];
    }
}

// ---------------- aggregation (R4 form): Z[nid,256:512] = sum_{in-nb} Z[src,0:256]
// half-wave (32 lanes) per node, 16B/lane (512B/row-gather), unroll x8 -> 8 row-gathers
// in flight. Rows walk src ascending (sorted cols) -> cohort-synchronized sweep.
__global__ void agg_kernel(unsigned short* __restrict__ base, long estride,
                           const int* __restrict__ rowstart, const unsigned short* __restrict__ cols,
                           const int* __restrict__ listp, const int* __restrict__ cntp) {
    unsigned short* Z = base + (long)blockIdx.y * estride;
    int half = threadIdx.x >> 5;               // 0..7
    int lane = threadIdx.x & 31;
    int idx = blockIdx.x * 8 + half;
    int limit = cntp ? cntp[blockIdx.y] : NN;
    if (idx >= limit) return;                  // half-wave uniform
    int nid = listp ? (listp[(long)blockIdx.y * NN + idx] & 0xFFFF) : idx;
    int s = rowstart[nid], e = rowstart[nid + 1];
    float acc[8] = {0.f, 0.f, 0.f, 0.f, 0.f, 0.f, 0.f, 0.f};
    int i = s;
    for (; i + 8 <= e; i += 8) {
        int c[8];
#pragma unroll
        for (int u = 0; u < 8; u++) c[u] = (int)cols[i + u];
        u16x8 v[8];
#pragma unroll
        for (int u = 0; u < 8; u++) v[u] = *(const u16x8*)&Z[(long)c[u] * KD + lane * 8];
#pragma unroll
        for (int u = 0; u < 8; u++)
#pragma unroll
            for (int j = 0; j < 8; j++) acc[j] += bf2f(v[u][j]);
    }
    for (; i < e; i++) {
        int c = (int)cols[i];
        u16x8 v = *(const u16x8*)&Z[(long)c * KD + lane * 8];
#pragma unroll
        for (int j = 0; j < 8; j++) acc[j] += bf2f(v[j]);
    }
    u16x8 o;
#pragma unroll
    for (int j = 0; j < 8; j++) o[j] = f2bf(acc[j]);
    *(u16x8*)&Z[(long)nid * KD + 256 + lane * 8] = o;
}

// ---------------- semantic router tail + softmax + top-2 + renormalize (wave per node)
__global__ void route_kernel(const unsigned short* __restrict__ T, const float* __restrict__ Ws2,
                             const float* __restrict__ bs2, const float* __restrict__ strug,
                             const int* __restrict__ batch, float* __restrict__ sparse,
                             int* __restrict__ topi) {
    int nid = blockIdx.x * 4 + (threadIdx.x >> 6);
    if (nid >= NN) return;
    int lane = threadIdx.x & 63;
    float s[8];
#pragma unroll
    for (int j = 0; j < 8; j++) s[j] = 0.f;
    ushort4 t4 = *(const ushort4*)&T[(long)nid * HH + lane * 4];
    float tv[4] = { bf2f(t4.x), bf2f(t4.y), bf2f(t4.z), bf2f(t4.w) };
#pragma unroll
    for (int kk = 0; kk < 4; kk++) {
        int k = lane * 4 + kk;
#pragma unroll
        for (int j = 0; j < 8; j++) s[j] += tv[kk] * Ws2[k * 8 + j];
    }
#pragma unroll
    for (int off = 32; off >= 1; off >>= 1) {
#pragma unroll
        for (int j = 0; j < 8; j++) s[j] += __shfl_xor(s[j], off, 64);
    }
    int g = batch[nid];
    float p[8], mx = -1e30f;
#pragma unroll
    for (int j = 0; j < 8; j++) {
        p[j] = 0.5f * (s[j] + bs2[j] + strug[g * 8 + j]);
        mx = fmaxf(mx, p[j]);
    }
    float ex[8];
#pragma unroll
    for (int j = 0; j < 8; j++) ex[j] = expf(p[j] - mx);
    int i1 = 0;
#pragma unroll
    for (int j = 1; j < 8; j++) if (ex[j] > ex[i1]) i1 = j;
    int i2 = (i1 == 0) ? 1 : 0;
#pragma unroll
    for (int j = 0; j < 8; j++) if (j != i1 && ex[j] > ex[i2]) i2 = j;
    float r = 1.f / (ex[i1] + ex[i2]);
    if (lane == 0) topi[nid] = i1 | (i2 << 8);
    if (lane < 8)
        sparse[(long)nid * 8 + lane] = (lane == i1) ? ex[i1] * r : (lane == i2) ? ex[i2] * r : 0.f;
}

// ---------------- per-expert selected-node lists; entries packed n | rank<<16
__global__ void build_lists(const float* __restrict__ sparse, const int* __restrict__ topi,
                            int* __restrict__ cnt, int* __restrict__ lists) {
    __shared__ int lc[NEXP], lb[NEXP];
    int tid = threadIdx.x;
    if (tid < NEXP) lc[tid] = 0;
    __syncthreads();
    int n = blockIdx.x * 256 + tid;
    int le_[2], pk_[2], ps_[2];
    int cc = 0;
    if (n < NN) {
        int t1 = topi[n] & 0xFF;
#pragma unroll
        for (int e = 0; e < NEXP; e++) {
            if (sparse[(long)n * 8 + e] > 0.f && cc < 2) {
                le_[cc] = e;
                pk_[cc] = n | ((e == t1) ? 0 : (1 << 16));
                ps_[cc] = atomicAdd(&lc[e], 1);
                cc++;
            }
        }
    }
    __syncthreads();
    if (tid < NEXP) lb[tid] = atomicAdd(&cnt[tid], lc[tid]);
    __syncthreads();
    for (int c = 0; c < cc; c++)
        lists[(long)le_[c] * NN + lb[le_[c]] + ps_[c]] = pk_[c];
}

// ---------------- MFMA GEMM: C[M,256] = A[M,K]_bf16 @ Bt[256,K]_bf16 (+bias)
// blockIdx.y = expert slot. gll16 staging, linear LDS + chunk^(row&7) XOR swizzle.
// MODE 0: relu, store bf16 (stride ldz). MODE 1: rows from packed list; store
// w * (acc+bias) bf16 into rank-disjoint outR planes.
template <int MODE>
__global__ __launch_bounds__(256, 2) void gemm_kernel(
    const unsigned short* __restrict__ A, long ae, int lda, int K,
    const unsigned short* __restrict__ Bt, long bte,
    const float* __restrict__ bias, int be_s,
    void* __restrict__ outp, long oe, int ldz,
    const float* __restrict__ sparse, int e0,
    const int* __restrict__ listp, const int* __restrict__ cntp) {
    __shared__ __align__(16) unsigned short Alds[MT * 64];
    __shared__ __align__(16) unsigned short Blds[HH * 64];
    __shared__ int nodeids[MT];
    const int el = blockIdx.y;
    const unsigned short* Ae = A + (long)el * ae;
    const unsigned short* Bte = Bt + (long)el * bte;
    const float* be = bias + (long)el * be_s;
    const int tid = threadIdx.x;
    const int wave = tid >> 6, lane = tid & 63;
    const int m = lane & 15, q = lane >> 4;
    const long row0 = (long)blockIdx.x * MT;

    if constexpr (MODE == 1) {
        int limit = cntp[el];
        if (row0 >= limit) return;              // uniform exit
        if (tid < MT) {
            long rr = row0 + tid;
            nodeids[tid] = (rr < limit) ? listp[(long)el * NN + rr] : -1;
        }
        __syncthreads();
    }

    const unsigned short* asrc[4];
#pragma unroll
    for (int i = 0; i < 4; i++) {
        int slot = tid + 256 * i;
        int r = slot >> 3, cg = (slot & 7) ^ (r & 7);
        long arow;
        if constexpr (MODE == 0) {
            arow = row0 + r;                    // padded rows < MPAD: garbage, masked on store
        } else {
            int v = nodeids[r];
            arow = (v >= 0) ? (v & 0xFFFF) : 0;
        }
        asrc[i] = Ae + arow * (long)lda + cg * 8;
    }
    const unsigned short* bsrc[8];
#pragma unroll
    for (int i = 0; i < 8; i++) {
        int slot = tid + 256 * i;
        int r = slot >> 3, cg = (slot & 7) ^ (r & 7);
        bsrc[i] = Bte + (long)r * K + cg * 8;
    }

    f32x4 acc[2][16];
#pragma unroll
    for (int i = 0; i < 2; i++)
#pragma unroll
        for (int j = 0; j < 16; j++) acc[i][j] = (f32x4){0.f, 0.f, 0.f, 0.f};

    const int swz = (m & 7) << 3;
    for (int k0 = 0; k0 < K; k0 += BK) {
#pragma unroll
        for (int i = 0; i < 4; i++) gll16(&Alds[(tid + 256 * i) * 8], asrc[i] + k0);
#pragma unroll
        for (int i = 0; i < 8; i++) gll16(&Blds[(tid + 256 * i) * 8], bsrc[i] + k0);
        __syncthreads();
#pragma unroll
        for (int kk = 0; kk < BK; kk += 32) {
            const int ch8 = (((kk >> 3) + q) << 3) ^ swz;
            const int ao = (wave * 32 + m) * 64 + ch8;
            bf16x8 a0 = *(const bf16x8*)&Alds[ao];
            bf16x8 a1 = *(const bf16x8*)&Alds[ao + 16 * 64];
#pragma unroll
            for (int ct = 0; ct < 16; ct++) {
                bf16x8 b = *(const bf16x8*)&Blds[(ct * 16 + m) * 64 + ch8];
                acc[0][ct] = __builtin_amdgcn_mfma_f32_16x16x32_bf16(a0, b, acc[0][ct], 0, 0, 0);
                acc[1][ct] = __builtin_amdgcn_mfma_f32_16x16x32_bf16(a1, b, acc[1][ct], 0, 0, 0);
            }
        }
        __syncthreads();
    }
    // epilogue: D layout col = lane&15, row = (lane>>4)*4 + reg
#pragma unroll
    for (int mt = 0; mt < 2; mt++) {
        int rtile = wave * 32 + mt * 16 + q * 4;
        if constexpr (MODE == 0) {
            unsigned short* oute = (unsigned short*)outp + (long)el * oe;
            long rbase = row0 + rtile;
#pragma unroll
            for (int ct = 0; ct < 16; ct++) {
                int col = ct * 16 + m;
                float bv = be[col];
#pragma unroll
                for (int r = 0; r < 4; r++) {
                    long grow = rbase + r;
                    if (grow < NN) {
                        float v = fmaxf(acc[mt][ct][r] + bv, 0.f);
                        oute[grow * ldz + col] = f2bf(v);
                    }
                }
            }
        } else {
            unsigned short* outR = (unsigned short*)outp;
            int v4[4]; float w4[4];
#pragma unroll
            for (int r = 0; r < 4; r++) {
                v4[r] = nodeids[rtile + r];
                w4[r] = (v4[r] >= 0) ? sparse[(long)(v4[r] & 0xFFFF) * 8 + e0 + el] : 0.f;
            }
#pragma unroll
            for (int ct = 0; ct < 16; ct++) {
                int col = ct * 16 + m;
                float bv = be[col];
#pragma unroll
                for (int r = 0; r < 4; r++) {
                    if (v4[r] >= 0) {
                        long nid = v4[r] & 0xFFFF;
                        long rank = (v4[r] >> 16) & 1;
                        outR[(rank * MPAD + nid) * HH + col] = f2bf(w4[r] * (acc[mt][ct][r] + bv));
                    }
                }
            }
        }
    }
}

// ---------------- final combine: out = rank0 + rank1 (weights already applied)
__global__ void combine_kernel(const unsigned short* __restrict__ outR, float* __restrict__ out) {
    long base = ((long)blockIdx.x * 256 + threadIdx.x) * 8;
    u16x8 r0 = *(const u16x8*)&outR[base];
    u16x8 r1 = *(const u16x8*)&outR[MPAD * HH + base];
    f32x4 lo, hi;
#pragma unroll
    for (int j = 0; j < 4; j++) lo[j] = bf2f(r0[j]) + bf2f(r1[j]);
#pragma unroll
    for (int j = 0; j < 4; j++) hi[j] = bf2f(r0[j + 4]) + bf2f(r1[j + 4]);
    *(f32x4*)&out[base] = lo;
    *(f32x4*)&out[base + 4] = hi;
}

extern "C" void kernel_launch(void* const* d_in, const int* in_sizes, int n_in,
                              void* d_out, int out_size, void* d_ws, size_t ws_size,
                              hipStream_t stream) {
    const float* x     = (const float*)d_in[0];
    const int*   ei    = (const int*)d_in[1];
    const int*   src   = ei;
    const int*   dst   = ei + EE;
    const int*   batch = (const int*)d_in[2];
    const float* W_enc = (const float*)d_in[3];
    const float* b_enc = (const float*)d_in[4];
    const float* Ws1   = (const float*)d_in[5];
    const float* bs1   = (const float*)d_in[6];
    const float* Ws2   = (const float*)d_in[7];
    const float* bs2   = (const float*)d_in[8];
    const float* Wt1   = (const float*)d_in[9];
    const float* bt1   = (const float*)d_in[10];
    const float* Wt2   = (const float*)d_in[11];
    const float* bt2   = (const float*)d_in[12];
    const float* W_self  = (const float*)d_in[13];
    const float* W_neigh = (const float*)d_in[14];
    const float* b_exp   = (const float*)d_in[15];
    float* out = (float*)d_out;

    char* ws = (char*)d_ws;
    size_t off = 0;
    auto alloc = [&](size_t b) { size_t p = off; off = (off + b + 255) & ~(size_t)255; return ws + p; };

    unsigned short* Ash  = (unsigned short*)alloc((size_t)MPAD * KD * 2);
    unsigned short* outR = (unsigned short*)alloc((size_t)2 * MPAD * HH * 2);
    unsigned short* Tbuf = outR;  // alias: router hidden consumed before outR first written
    unsigned short* BtE = (unsigned short*)alloc((size_t)NEXP * LAY * HH * KD * 2);
    unsigned short* Bt1 = (unsigned short*)alloc((size_t)HH * HH * 2);
    float* sparse  = (float*)alloc((size_t)NN * 8 * 4);
    int* topi      = (int*)alloc((size_t)NN * 4);
    float* strug   = (float*)alloc((size_t)GG * 8 * 4);
    int* ecnt      = (int*)alloc((size_t)GG * 4);
    int* deg       = (int*)alloc((size_t)NN * 4);
    int* rowstart  = (int*)alloc((size_t)(NN + 1) * 4);
    unsigned short* perm = (unsigned short*)alloc((size_t)EE * 2);
    unsigned short* cols = (unsigned short*)alloc((size_t)EE * 2);
    int* lists     = (int*)alloc((size_t)NEXP * NN * 4);
    int* cnt8      = (int*)alloc((size_t)NEXP * 4);

    // expert z-buffers fill the rest of the workspace; group size adapts to ws_size.
    const long BUFS = MPAD * KD;                 // elements per expert buffer
    long avail = ((long)ws_size - (long)off) / (BUFS * 2);
    int EG = (avail < 1) ? 1 : (avail > NEXP ? NEXP : (int)avail);
    unsigned short* bufs = (unsigned short*)(ws + off);

    hipMemsetAsync(ecnt, 0, GG * 4, stream);
    hipMemsetAsync(deg, 0, (size_t)NN * 4, stream);
    hipMemsetAsync(cnt8, 0, NEXP * 4, stream);

    pack_experts<<<NEXP * LAY * KD * HH / 256, 256, 0, stream>>>(W_self, W_neigh, BtE);
    pack_ws1<<<HH * HH / 256, 256, 0, stream>>>(Ws1, Bt1);
    encoder_kernel<<<NN, HH, 0, stream>>>(x, W_enc, b_enc, Ash);

    degp_kernel<<<(EE + 255) / 256, 256, 0, stream>>>(dst, deg, perm);
    hist2_kernel<<<HBLK, 256, 0, stream>>>(src, batch, ecnt);
    scan_kernel<<<1, 1024, 0, stream>>>(deg, rowstart);
    scatter2_kernel<<<(EE + 255) / 256, 256, 0, stream>>>(src, dst, perm, rowstart, cols);
    psort_kernel<<<AGB, 256, 0, stream>>>(rowstart, cols);
    stru_kernel<<<GG, HH, 0, stream>>>(batch, ecnt, Wt1, bt1, Wt2, bt2, strug);

    // semantic router hidden: T = relu(h @ Ws1 + bs1)
    gemm_kernel<0><<<dim3(GB, 1), 256, 0, stream>>>(Ash, 0, KD, HH, Bt1, 0, bs1, 0,
                                                    Tbuf, 0, HH, nullptr, 0, nullptr, nullptr);
    route_kernel<<<(NN + 3) / 4, 256, 0, stream>>>(Tbuf, Ws2, bs2, strug, batch, sparse, topi);
    build_lists<<<(NN + 255) / 256, 256, 0, stream>>>(sparse, topi, cnt8, lists);

    // shared layer-0 aggregation: Ash[:,256:512] = A . h  (reused by all 8 experts)
    agg_kernel<<<dim3(AGB, 1), 256, 0, stream>>>(Ash, 0, rowstart, cols, nullptr, nullptr);

    const long BTL = (long)LAY * HH * KD;
    for (int e0 = 0; e0 < NEXP; e0 += EG) {
        int eg = (NEXP - e0 < EG) ? (NEXP - e0) : EG;
        dim3 gg(GB, eg), ga(AGB, eg);
        // layer 0: z1 = relu([h|agg0] @ B0) -> bufs cols 0:255
        gemm_kernel<0><<<gg, 256, 0, stream>>>(Ash, 0, KD, KD,
                                               BtE + (size_t)(e0 * LAY + 0) * HH * KD, BTL,
                                               b_exp + (size_t)e0 * LAY * HH, LAY * HH,
                                               bufs, BUFS, KD, nullptr, 0, nullptr, nullptr);
        agg_kernel<<<ga, 256, 0, stream>>>(bufs, BUFS, rowstart, cols, nullptr, nullptr);
        // layer 1 IN-PLACE: z2 overwrites z1 cols 0:255 (tile rows fully read before epilogue)
        gemm_kernel<0><<<gg, 256, 0, stream>>>(bufs, BUFS, KD, KD,
                                               BtE + (size_t)(e0 * LAY + 1) * HH * KD, BTL,
                                               b_exp + (size_t)e0 * LAY * HH + HH, LAY * HH,
                                               bufs, BUFS, KD, nullptr, 0, nullptr, nullptr);
        agg_kernel<<<ga, 256, 0, stream>>>(bufs, BUFS, rowstart, cols,
                                           lists + (size_t)e0 * NN, cnt8 + e0);
        // layer 2 on selected rows -> rank-disjoint outR (race-free across experts)
        gemm_kernel<1><<<gg, 256, 0, stream>>>(bufs, BUFS, KD, KD,
                                               BtE + (size_t)(e0 * LAY + 2) * HH * KD, BTL,
                                               b_exp + (size_t)e0 * LAY * HH + 2 * HH, LAY * HH,
                                               outR, 0, 0, sparse, e0,
                                               lists + (size_t)e0 * NN, cnt8 + e0);
    }
    combine_kernel<<<NN * HH / 8 / 256, 256, 0, stream>>>(outR, out);
}

// Round 8
// 2107.803 us; speedup vs baseline: 1.1265x; 1.0210x over previous
//
#include <hip/hip_runtime.h>

// GraphMoE dual router: encoder -> routers -> 8 GraphConv experts (3 layers) -> sparse combine.
// R1: agg latency fix: half-wave/node, 16B/lane, 8 row-gathers in flight.
// R2/R3: ushort cols, top-2 sparsity on layer-2.
// R4: 1-atomic CSR (perm), atomic-free scatter, gll16+XOR-swizzle GEMM, rank-disjoint outR. 2168us.
// R5 FAILED (2378): role-fused gemm||agg — GEMM footprint caps agg occupancy.
// R6 FAILED (2597): agg column-slicing: 64B gathers destroyed L2 reuse.
// R7 FAILED (2245): 16-deep agg unroll: VGPR 40->64, occ 57->39%. ILP lever dead.
// R8 FAILED (2374): degree-sorted node order; FETCH order-sensitivity discovered.
// R9 MIXED (2348): sorted-cols sweep helps agg ~56us; serial sort cost 236us.
// R10 WIN (2152): half-wave register bitonic sort (~free). Agg at its latency/L2 floor
//   (instantaneous sweep window ~9MB > 4MB/XCD L2; further locality needs partial passes).
// R11 (this round): GEMM inner loop is LDS-READ-bound: wave=32rowsx256cols -> per kk
//   2 A + 16 B ds_read_b128 per 32 MFMA = 216 vs 160 cyc. Re-partition waves 2x2 over
//   (64 rows x 128 cols): 4 A + 8 B per 32 MFMA = 144 vs 160 -> MFMA-bound. acc stays
//   4x8xf32x4 = 128 VGPR; staging/sync/swizzle untouched. Predict L0/L1 60->~47us,
//   MfmaUtil +10pts, total ~2020. If GEMM unmoved -> 8-phase 256^2 port next.

#define NN 50000
#define EE 1600000
#define GG 64
#define HH 256
#define NEXP 8
#define LAY 3
#define KD 512          // concat K = [z | agg]
#define MT 128          // GEMM row tile per block
#define BK 64           // GEMM K tile
#define GB 391          // (NN + MT - 1) / MT
#define AGB 6250        // NN / 8 agg blocks (8 half-waves each)
#define MPAD 50048L     // 391 * 128

typedef __attribute__((ext_vector_type(8))) short bf16x8;
typedef __attribute__((ext_vector_type(8))) unsigned short u16x8;
typedef __attribute__((ext_vector_type(4))) float f32x4;

__device__ __forceinline__ float bf2f(unsigned short u) {
    union { unsigned int i; float f; } v; v.i = ((unsigned int)u) << 16; return v.f;
}
__device__ __forceinline__ unsigned short f2bf(float f) {
    union { unsigned int i; float f; } v; v.f = f;
    unsigned int r = (v.i + 0x7FFFu + ((v.i >> 16) & 1u)) >> 16;
    return (unsigned short)r;
}
__device__ __forceinline__ void gll16(unsigned short* l, const unsigned short* g) {
    __builtin_amdgcn_global_load_lds((__attribute__((address_space(1))) void*)g,
                                     (__attribute__((address_space(3))) void*)l, 16, 0, 0);
}

// ---------------- encoder: h = relu(x[:,4:10] @ W_enc + b_enc), bf16 into Ash cols 0..255
__global__ void encoder_kernel(const float* __restrict__ x, const float* __restrict__ W,
                               const float* __restrict__ b, unsigned short* __restrict__ out) {
    int n = blockIdx.x, j = threadIdx.x;
    float acc = b[j];
#pragma unroll
    for (int i = 0; i < 6; i++) acc += x[n * 10 + 4 + i] * W[i * HH + j];
    acc = fmaxf(acc, 0.f);
    out[(long)n * KD + j] = f2bf(acc);
}

// ---------------- weight packing: Bt[(e*3+l)][n][k] bf16, k<256 -> W_self, k>=256 -> W_neigh
__global__ void pack_experts(const float* __restrict__ Wself, const float* __restrict__ Wneigh,
                             unsigned short* __restrict__ Bt) {
    int idx = blockIdx.x * 256 + threadIdx.x;          // (e,l,k,n), n fastest
    int n = idx & 255; int r = idx >> 8;
    int k = r & 511; r >>= 9;
    int l = r % LAY; int e = r / LAY;
    float v = (k < 256) ? Wself[(((e * LAY + l) * HH) + k) * HH + n]
                        : Wneigh[(((e * LAY + l) * HH) + (k - 256)) * HH + n];
    Bt[(((long)(e * LAY + l) * HH + n) * KD) + k] = f2bf(v);
}

__global__ void pack_ws1(const float* __restrict__ W, unsigned short* __restrict__ Bt) {
    int idx = blockIdx.x * 256 + threadIdx.x;
    int n = idx & 255; int k = idx >> 8;
    Bt[(long)n * HH + k] = f2bf(W[k * HH + n]);
}

// ---------------- degree pass: ONE atomic per edge; returned old value = within-row slot.
__global__ void degp_kernel(const int* __restrict__ dst, int* __restrict__ deg,
                            unsigned short* __restrict__ perm) {
    int e = blockIdx.x * 256 + threadIdx.x;
    if (e < EE) perm[e] = (unsigned short)atomicAdd(&deg[dst[e]], 1);  // max in-degree << 65536
}

// ---------------- per-graph edge histogram via ballot: 1 ballot/edge, no per-edge atomics.
#define HBLK 128
#define HITER ((EE + HBLK * 256 - 1) / (HBLK * 256))
__global__ void hist2_kernel(const int* __restrict__ src, const int* __restrict__ batch,
                             int* __restrict__ ecnt) {
    __shared__ int h[GG];
    if (threadIdx.x < GG) h[threadIdx.x] = 0;
    __syncthreads();
    int lane = threadIdx.x & 63;
    int gid = blockIdx.x * 256 + threadIdx.x;
    int cnt = 0;
    for (int it = 0; it < HITER; it++) {
        long e = (long)it * (HBLK * 256) + gid;
        int g = (e < EE) ? batch[src[e]] : -1;
        for (int gg = 0; gg < GG; gg++) {
            unsigned long long m = __ballot(g == gg);
            if (lane == gg) cnt += (int)__popcll(m);
        }
    }
    atomicAdd(&h[lane], cnt);
    __syncthreads();
    if (threadIdx.x < GG && h[threadIdx.x]) atomicAdd(&ecnt[threadIdx.x], h[threadIdx.x]);
}

// ---------------- structural router per graph; node count via binary search on sorted batch
__global__ void stru_kernel(const int* __restrict__ batch, const int* __restrict__ ecnt,
                            const float* __restrict__ Wt1, const float* __restrict__ bt1,
                            const float* __restrict__ Wt2, const float* __restrict__ bt2,
                            float* __restrict__ strug) {
    __shared__ float t[HH];
    __shared__ int nc;
    int g = blockIdx.x, j = threadIdx.x;
    if (j == 0) {
        int lo = 0, hi = NN;
        while (lo < hi) { int mid = (lo + hi) >> 1; if (batch[mid] < g) lo = mid + 1; else hi = mid; }
        int s = lo; lo = 0; hi = NN;
        while (lo < hi) { int mid = (lo + hi) >> 1; if (batch[mid] < g + 1) lo = mid + 1; else hi = mid; }
        nc = lo - s;
    }
    __syncthreads();
    float nf = log1pf((float)nc);
    float ef = log1pf((float)ecnt[g]);
    float v = nf * Wt1[j] + ef * Wt1[HH + j] + bt1[j];
    t[j] = fmaxf(v, 0.f);
    __syncthreads();
    if (j < 8) {
        float sum = bt2[j];
        for (int k = 0; k < HH; k++) sum += t[k] * Wt2[k * 8 + j];
        strug[g * 8 + j] = sum;
    }
}

// single block, 1024 threads; shuffle-based inclusive scan
__global__ void scan_kernel(const int* __restrict__ deg, int* __restrict__ rowstart) {
    __shared__ int wsum[16];
    __shared__ int carry_s;
    int tid = threadIdx.x;
    int wid = tid >> 6, lane = tid & 63;
    if (tid == 0) carry_s = 0;
    __syncthreads();
    for (int base = 0; base < NN; base += 1024) {
        int i = base + tid;
        int v = (i < NN) ? deg[i] : 0;
        int sc = v;
#pragma unroll
        for (int off = 1; off < 64; off <<= 1) {
            int t = __shfl_up(sc, off, 64);
            if (lane >= off) sc += t;
        }
        if (lane == 63) wsum[wid] = sc;
        __syncthreads();
        int carry = carry_s;
        int prev = 0;
        for (int w = 0; w < wid; w++) prev += wsum[w];
        int excl = carry + prev + sc - v;
        if (i < NN) rowstart[i] = excl;
        __syncthreads();
        if (tid == 1023) carry_s = carry + prev + sc;
    }
    __syncthreads();
    if (tid == 0) rowstart[NN] = carry_s;
}

// ---------------- atomic-free scatter: position = rowstart[dst] + perm
__global__ void scatter2_kernel(const int* __restrict__ src, const int* __restrict__ dst,
                                const unsigned short* __restrict__ perm,
                                const int* __restrict__ rowstart,
                                unsigned short* __restrict__ cols) {
    int e = blockIdx.x * 256 + threadIdx.x;
    if (e < EE) cols[rowstart[dst[e]] + (int)perm[e]] = (unsigned short)src[e];
}

// ---------------- per-row src sort, half-wave bitonic: 32 lanes x 4 regs = 128-slot network.
__global__ void psort_kernel(const int* __restrict__ rowstart, unsigned short* __restrict__ cols) {
    int half = threadIdx.x >> 5;
    int lane = threadIdx.x & 31;
    int n = blockIdx.x * 8 + half;
    if (n >= NN) return;
    int s = rowstart[n], e = rowstart[n + 1];
    int d = e - s;
    if (d <= 1) return;
    if (d > 128) {                       // safety fallback; Poisson(32) never hits this
        if (lane == 0) {
            for (int i = s + 1; i < e; i++) {
                unsigned short key = cols[i];
                int j = i - 1;
                while (j >= s && cols[j] > key) { cols[j + 1] = cols[j]; j--; }
                cols[j + 1] = key;
            }
        }
        return;
    }
    unsigned int r[4];
#pragma unroll
    for (int i = 0; i < 4; i++) {
        int v = i * 32 + lane;
        r[i] = (v < d) ? (unsigned int)cols[s + v] : 0xFFFFu;
    }
#pragma unroll
    for (int k = 2; k <= 128; k <<= 1) {
#pragma unroll
        for (int j = 64; j > 0; j >>= 1) {
            if (j >= k) continue;        // run stages j = k/2 .. 1
            if (j >= 32) {
                int js = j >> 5;
#pragma unroll
                for (int i = 0; i < 4; i++) {
                    int i2 = i ^ js;
                    if (i < i2) {
                        int v = i * 32 + lane;
                        unsigned int a = r[i], b = r[i2];
                        unsigned int mn = a < b ? a : b, mx = a < b ? b : a;
                        bool up = (v & k) == 0;
                        r[i]  = up ? mn : mx;
                        r[i2] = up ? mx : mn;
                    }
                }
            } else {
#pragma unroll
                for (int i = 0; i < 4; i++) {
                    int v = i * 32 + lane;
                    unsigned int p = (unsigned int)__shfl_xor((int)r[i], j, 32);
                    unsigned int mn = r[i] < p ? r[i] : p, mx = r[i] < p ? p : r[i];
                    bool up = (v & k) == 0;
                    bool lo = (v & j) == 0;
                    r[i] = (up == lo) ? mn : mx;
                }
            }
        }
    }
#pragma unroll
    for (int i = 0; i < 4; i++) {
        int v = i * 32 + lane;
        if (v < d) cols[s + v] = (unsigned short)r[i];
    }
}

// ---------------- aggregation: Z[nid,256:512] = sum_{in-nb} Z[src,0:256]
// half-wave (32 lanes) per node, 16B/lane, unroll x8; sorted cols -> synchronized sweep.
__global__ void agg_kernel(unsigned short* __restrict__ base, long estride,
                           const int* __restrict__ rowstart, const unsigned short* __restrict__ cols,
                           const int* __restrict__ listp, const int* __restrict__ cntp) {
    unsigned short* Z = base + (long)blockIdx.y * estride;
    int half = threadIdx.x >> 5;               // 0..7
    int lane = threadIdx.x & 31;
    int idx = blockIdx.x * 8 + half;
    int limit = cntp ? cntp[blockIdx.y] : NN;
    if (idx >= limit) return;                  // half-wave uniform
    int nid = listp ? (listp[(long)blockIdx.y * NN + idx] & 0xFFFF) : idx;
    int s = rowstart[nid], e = rowstart[nid + 1];
    float acc[8] = {0.f, 0.f, 0.f, 0.f, 0.f, 0.f, 0.f, 0.f};
    int i = s;
    for (; i + 8 <= e; i += 8) {
        int c[8];
#pragma unroll
        for (int u = 0; u < 8; u++) c[u] = (int)cols[i + u];
        u16x8 v[8];
#pragma unroll
        for (int u = 0; u < 8; u++) v[u] = *(const u16x8*)&Z[(long)c[u] * KD + lane * 8];
#pragma unroll
        for (int u = 0; u < 8; u++)
#pragma unroll
            for (int j = 0; j < 8; j++) acc[j] += bf2f(v[u][j]);
    }
    for (; i < e; i++) {
        int c = (int)cols[i];
        u16x8 v = *(const u16x8*)&Z[(long)c * KD + lane * 8];
#pragma unroll
        for (int j = 0; j < 8; j++) acc[j] += bf2f(v[j]);
    }
    u16x8 o;
#pragma unroll
    for (int j = 0; j < 8; j++) o[j] = f2bf(acc[j]);
    *(u16x8*)&Z[(long)nid * KD + 256 + lane * 8] = o;
}

// ---------------- semantic router tail + softmax + top-2 + renormalize (wave per node)
__global__ void route_kernel(const unsigned short* __restrict__ T, const float* __restrict__ Ws2,
                             const float* __restrict__ bs2, const float* __restrict__ strug,
                             const int* __restrict__ batch, float* __restrict__ sparse,
                             int* __restrict__ topi) {
    int nid = blockIdx.x * 4 + (threadIdx.x >> 6);
    if (nid >= NN) return;
    int lane = threadIdx.x & 63;
    float s[8];
#pragma unroll
    for (int j = 0; j < 8; j++) s[j] = 0.f;
    ushort4 t4 = *(const ushort4*)&T[(long)nid * HH + lane * 4];
    float tv[4] = { bf2f(t4.x), bf2f(t4.y), bf2f(t4.z), bf2f(t4.w) };
#pragma unroll
    for (int kk = 0; kk < 4; kk++) {
        int k = lane * 4 + kk;
#pragma unroll
        for (int j = 0; j < 8; j++) s[j] += tv[kk] * Ws2[k * 8 + j];
    }
#pragma unroll
    for (int off = 32; off >= 1; off >>= 1) {
#pragma unroll
        for (int j = 0; j < 8; j++) s[j] += __shfl_xor(s[j], off, 64);
    }
    int g = batch[nid];
    float p[8], mx = -1e30f;
#pragma unroll
    for (int j = 0; j < 8; j++) {
        p[j] = 0.5f * (s[j] + bs2[j] + strug[g * 8 + j]);
        mx = fmaxf(mx, p[j]);
    }
    float ex[8];
#pragma unroll
    for (int j = 0; j < 8; j++) ex[j] = expf(p[j] - mx);
    int i1 = 0;
#pragma unroll
    for (int j = 1; j < 8; j++) if (ex[j] > ex[i1]) i1 = j;
    int i2 = (i1 == 0) ? 1 : 0;
#pragma unroll
    for (int j = 0; j < 8; j++) if (j != i1 && ex[j] > ex[i2]) i2 = j;
    float r = 1.f / (ex[i1] + ex[i2]);
    if (lane == 0) topi[nid] = i1 | (i2 << 8);
    if (lane < 8)
        sparse[(long)nid * 8 + lane] = (lane == i1) ? ex[i1] * r : (lane == i2) ? ex[i2] * r : 0.f;
}

// ---------------- per-expert selected-node lists; entries packed n | rank<<16
__global__ void build_lists(const float* __restrict__ sparse, const int* __restrict__ topi,
                            int* __restrict__ cnt, int* __restrict__ lists) {
    __shared__ int lc[NEXP], lb[NEXP];
    int tid = threadIdx.x;
    if (tid < NEXP) lc[tid] = 0;
    __syncthreads();
    int n = blockIdx.x * 256 + tid;
    int le_[2], pk_[2], ps_[2];
    int cc = 0;
    if (n < NN) {
        int t1 = topi[n] & 0xFF;
#pragma unroll
        for (int e = 0; e < NEXP; e++) {
            if (sparse[(long)n * 8 + e] > 0.f && cc < 2) {
                le_[cc] = e;
                pk_[cc] = n | ((e == t1) ? 0 : (1 << 16));
                ps_[cc] = atomicAdd(&lc[e], 1);
                cc++;
            }
        }
    }
    __syncthreads();
    if (tid < NEXP) lb[tid] = atomicAdd(&cnt[tid], lc[tid]);
    __syncthreads();
    for (int c = 0; c < cc; c++)
        lists[(long)le_[c] * NN + lb[le_[c]] + ps_[c]] = pk_[c];
}

// ---------------- MFMA GEMM: C[M,256] = A[M,K]_bf16 @ Bt[256,K]_bf16 (+bias)
// blockIdx.y = expert slot. gll16 staging, linear LDS + chunk^(row&7) XOR swizzle.
// R11: waves 2x2 over (64 rows x 128 cols): per kk 4 A + 8 B ds_read_b128 per 32 MFMA
// (was 2 A + 16 B per 32) -> inner loop MFMA-bound instead of LDS-read-bound.
// MODE 0: relu, store bf16 (stride ldz). MODE 1: rows from packed list; store
// w * (acc+bias) bf16 into rank-disjoint outR planes.
template <int MODE>
__global__ __launch_bounds__(256, 2) void gemm_kernel(
    const unsigned short* __restrict__ A, long ae, int lda, int K,
    const unsigned short* __restrict__ Bt, long bte,
    const float* __restrict__ bias, int be_s,
    void* __restrict__ outp, long oe, int ldz,
    const float* __restrict__ sparse, int e0,
    const int* __restrict__ listp, const int* __restrict__ cntp) {
    __shared__ __align__(16) unsigned short Alds[MT * 64];
    __shared__ __align__(16) unsigned short Blds[HH * 64];
    __shared__ int nodeids[MT];
    const int el = blockIdx.y;
    const unsigned short* Ae = A + (long)el * ae;
    const unsigned short* Bte = Bt + (long)el * bte;
    const float* be = bias + (long)el * be_s;
    const int tid = threadIdx.x;
    const int wave = tid >> 6, lane = tid & 63;
    const int wr = wave >> 1, wc = wave & 1;    // 2x2 wave grid
    const int m = lane & 15, q = lane >> 4;
    const long row0 = (long)blockIdx.x * MT;

    if constexpr (MODE == 1) {
        int limit = cntp[el];
        if (row0 >= limit) return;              // uniform exit
        if (tid < MT) {
            long rr = row0 + tid;
            nodeids[tid] = (rr < limit) ? listp[(long)el * NN + rr] : -1;
        }
        __syncthreads();
    }

    const unsigned short* asrc[4];
#pragma unroll
    for (int i = 0; i < 4; i++) {
        int slot = tid + 256 * i;
        int r = slot >> 3, cg = (slot & 7) ^ (r & 7);
        long arow;
        if constexpr (MODE == 0) {
            arow = row0 + r;                    // padded rows < MPAD: garbage, masked on store
        } else {
            int v = nodeids[r];
            arow = (v >= 0) ? (v & 0xFFFF) : 0;
        }
        asrc[i] = Ae + arow * (long)lda + cg * 8;
    }
    const unsigned short* bsrc[8];
#pragma unroll
    for (int i = 0; i < 8; i++) {
        int slot = tid + 256 * i;
        int r = slot >> 3, cg = (slot & 7) ^ (r & 7);
        bsrc[i] = Bte + (long)r * K + cg * 8;
    }

    f32x4 acc[4][8];
#pragma unroll
    for (int i = 0; i < 4; i++)
#pragma unroll
        for (int j = 0; j < 8; j++) acc[i][j] = (f32x4){0.f, 0.f, 0.f, 0.f};

    const int swz = (m & 7) << 3;
    for (int k0 = 0; k0 < K; k0 += BK) {
#pragma unroll
        for (int i = 0; i < 4; i++) gll16(&Alds[(tid + 256 * i) * 8], asrc[i] + k0);
#pragma unroll
        for (int i = 0; i < 8; i++) gll16(&Blds[(tid + 256 * i) * 8], bsrc[i] + k0);
        __syncthreads();
#pragma unroll
        for (int kk = 0; kk < BK; kk += 32) {
            const int ch8 = (((kk >> 3) + q) << 3) ^ swz;
            bf16x8 a[4];
#pragma unroll
            for (int mf = 0; mf < 4; mf++)
                a[mf] = *(const bf16x8*)&Alds[(wr * 64 + mf * 16 + m) * 64 + ch8];
#pragma unroll
            for (int ct = 0; ct < 8; ct++) {
                bf16x8 b = *(const bf16x8*)&Blds[(wc * 128 + ct * 16 + m) * 64 + ch8];
#pragma unroll
                for (int mf = 0; mf < 4; mf++)
                    acc[mf][ct] = __builtin_amdgcn_mfma_f32_16x16x32_bf16(a[mf], b, acc[mf][ct], 0, 0, 0);
            }
        }
        __syncthreads();
    }
    // epilogue: D layout col = lane&15, row = (lane>>4)*4 + reg
#pragma unroll
    for (int mf = 0; mf < 4; mf++) {
        int rtile = wr * 64 + mf * 16 + q * 4;
        if constexpr (MODE == 0) {
            unsigned short* oute = (unsigned short*)outp + (long)el * oe;
            long rbase = row0 + rtile;
#pragma unroll
            for (int ct = 0; ct < 8; ct++) {
                int col = wc * 128 + ct * 16 + m;
                float bv = be[col];
#pragma unroll
                for (int r = 0; r < 4; r++) {
                    long grow = rbase + r;
                    if (grow < NN) {
                        float v = fmaxf(acc[mf][ct][r] + bv, 0.f);
                        oute[grow * ldz + col] = f2bf(v);
                    }
                }
            }
        } else {
            unsigned short* outR = (unsigned short*)outp;
            int v4[4]; float w4[4];
#pragma unroll
            for (int r = 0; r < 4; r++) {
                v4[r] = nodeids[rtile + r];
                w4[r] = (v4[r] >= 0) ? sparse[(long)(v4[r] & 0xFFFF) * 8 + e0 + el] : 0.f;
            }
#pragma unroll
            for (int ct = 0; ct < 8; ct++) {
                int col = wc * 128 + ct * 16 + m;
                float bv = be[col];
#pragma unroll
                for (int r = 0; r < 4; r++) {
                    if (v4[r] >= 0) {
                        long nid = v4[r] & 0xFFFF;
                        long rank = (v4[r] >> 16) & 1;
                        outR[(rank * MPAD + nid) * HH + col] = f2bf(w4[r] * (acc[mf][ct][r] + bv));
                    }
                }
            }
        }
    }
}

// ---------------- final combine: out = rank0 + rank1 (weights already applied)
__global__ void combine_kernel(const unsigned short* __restrict__ outR, float* __restrict__ out) {
    long base = ((long)blockIdx.x * 256 + threadIdx.x) * 8;
    u16x8 r0 = *(const u16x8*)&outR[base];
    u16x8 r1 = *(const u16x8*)&outR[MPAD * HH + base];
    f32x4 lo, hi;
#pragma unroll
    for (int j = 0; j < 4; j++) lo[j] = bf2f(r0[j]) + bf2f(r1[j]);
#pragma unroll
    for (int j = 0; j < 4; j++) hi[j] = bf2f(r0[j + 4]) + bf2f(r1[j + 4]);
    *(f32x4*)&out[base] = lo;
    *(f32x4*)&out[base + 4] = hi;
}

extern "C" void kernel_launch(void* const* d_in, const int* in_sizes, int n_in,
                              void* d_out, int out_size, void* d_ws, size_t ws_size,
                              hipStream_t stream) {
    const float* x     = (const float*)d_in[0];
    const int*   ei    = (const int*)d_in[1];
    const int*   src   = ei;
    const int*   dst   = ei + EE;
    const int*   batch = (const int*)d_in[2];
    const float* W_enc = (const float*)d_in[3];
    const float* b_enc = (const float*)d_in[4];
    const float* Ws1   = (const float*)d_in[5];
    const float* bs1   = (const float*)d_in[6];
    const float* Ws2   = (const float*)d_in[7];
    const float* bs2   = (const float*)d_in[8];
    const float* Wt1   = (const float*)d_in[9];
    const float* bt1   = (const float*)d_in[10];
    const float* Wt2   = (const float*)d_in[11];
    const float* bt2   = (const float*)d_in[12];
    const float* W_self  = (const float*)d_in[13];
    const float* W_neigh = (const float*)d_in[14];
    const float* b_exp   = (const float*)d_in[15];
    float* out = (float*)d_out;

    char* ws = (char*)d_ws;
    size_t off = 0;
    auto alloc = [&](size_t b) { size_t p = off; off = (off + b + 255) & ~(size_t)255; return ws + p; };

    unsigned short* Ash  = (unsigned short*)alloc((size_t)MPAD * KD * 2);
    unsigned short* outR = (unsigned short*)alloc((size_t)2 * MPAD * HH * 2);
    unsigned short* Tbuf = outR;  // alias: router hidden consumed before outR first written
    unsigned short* BtE = (unsigned short*)alloc((size_t)NEXP * LAY * HH * KD * 2);
    unsigned short* Bt1 = (unsigned short*)alloc((size_t)HH * HH * 2);
    float* sparse  = (float*)alloc((size_t)NN * 8 * 4);
    int* topi      = (int*)alloc((size_t)NN * 4);
    float* strug   = (float*)alloc((size_t)GG * 8 * 4);
    int* ecnt      = (int*)alloc((size_t)GG * 4);
    int* deg       = (int*)alloc((size_t)NN * 4);
    int* rowstart  = (int*)alloc((size_t)(NN + 1) * 4);
    unsigned short* perm = (unsigned short*)alloc((size_t)EE * 2);
    unsigned short* cols = (unsigned short*)alloc((size_t)EE * 2);
    int* lists     = (int*)alloc((size_t)NEXP * NN * 4);
    int* cnt8      = (int*)alloc((size_t)NEXP * 4);

    // expert z-buffers fill the rest of the workspace; group size adapts to ws_size.
    const long BUFS = MPAD * KD;                 // elements per expert buffer
    long avail = ((long)ws_size - (long)off) / (BUFS * 2);
    int EG = (avail < 1) ? 1 : (avail > NEXP ? NEXP : (int)avail);
    unsigned short* bufs = (unsigned short*)(ws + off);

    hipMemsetAsync(ecnt, 0, GG * 4, stream);
    hipMemsetAsync(deg, 0, (size_t)NN * 4, stream);
    hipMemsetAsync(cnt8, 0, NEXP * 4, stream);

    pack_experts<<<NEXP * LAY * KD * HH / 256, 256, 0, stream>>>(W_self, W_neigh, BtE);
    pack_ws1<<<HH * HH / 256, 256, 0, stream>>>(Ws1, Bt1);
    encoder_kernel<<<NN, HH, 0, stream>>>(x, W_enc, b_enc, Ash);

    degp_kernel<<<(EE + 255) / 256, 256, 0, stream>>>(dst, deg, perm);
    hist2_kernel<<<HBLK, 256, 0, stream>>>(src, batch, ecnt);
    scan_kernel<<<1, 1024, 0, stream>>>(deg, rowstart);
    scatter2_kernel<<<(EE + 255) / 256, 256, 0, stream>>>(src, dst, perm, rowstart, cols);
    psort_kernel<<<AGB, 256, 0, stream>>>(rowstart, cols);
    stru_kernel<<<GG, HH, 0, stream>>>(batch, ecnt, Wt1, bt1, Wt2, bt2, strug);

    // semantic router hidden: T = relu(h @ Ws1 + bs1)
    gemm_kernel<0><<<dim3(GB, 1), 256, 0, stream>>>(Ash, 0, KD, HH, Bt1, 0, bs1, 0,
                                                    Tbuf, 0, HH, nullptr, 0, nullptr, nullptr);
    route_kernel<<<(NN + 3) / 4, 256, 0, stream>>>(Tbuf, Ws2, bs2, strug, batch, sparse, topi);
    build_lists<<<(NN + 255) / 256, 256, 0, stream>>>(sparse, topi, cnt8, lists);

    // shared layer-0 aggregation: Ash[:,256:512] = A . h  (reused by all 8 experts)
    agg_kernel<<<dim3(AGB, 1), 256, 0, stream>>>(Ash, 0, rowstart, cols, nullptr, nullptr);

    const long BTL = (long)LAY * HH * KD;
    for (int e0 = 0; e0 < NEXP; e0 += EG) {
        int eg = (NEXP - e0 < EG) ? (NEXP - e0) : EG;
        dim3 gg(GB, eg), ga(AGB, eg);
        // layer 0: z1 = relu([h|agg0] @ B0) -> bufs cols 0:255
        gemm_kernel<0><<<gg, 256, 0, stream>>>(Ash, 0, KD, KD,
                                               BtE + (size_t)(e0 * LAY + 0) * HH * KD, BTL,
                                               b_exp + (size_t)e0 * LAY * HH, LAY * HH,
                                               bufs, BUFS, KD, nullptr, 0, nullptr, nullptr);
        agg_kernel<<<ga, 256, 0, stream>>>(bufs, BUFS, rowstart, cols, nullptr, nullptr);
        // layer 1 IN-PLACE: z2 overwrites z1 cols 0:255 (tile rows fully read before epilogue)
        gemm_kernel<0><<<gg, 256, 0, stream>>>(bufs, BUFS, KD, KD,
                                               BtE + (size_t)(e0 * LAY + 1) * HH * KD, BTL,
                                               b_exp + (size_t)e0 * LAY * HH + HH, LAY * HH,
                                               bufs, BUFS, KD, nullptr, 0, nullptr, nullptr);
        agg_kernel<<<ga, 256, 0, stream>>>(bufs, BUFS, rowstart, cols,
                                           lists + (size_t)e0 * NN, cnt8 + e0);
        // layer 2 on selected rows -> rank-disjoint outR (race-free across experts)
        gemm_kernel<1><<<gg, 256, 0, stream>>>(bufs, BUFS, KD, KD,
                                               BtE + (size_t)(e0 * LAY + 2) * HH * KD, BTL,
                                               b_exp + (size_t)e0 * LAY * HH + 2 * HH, LAY * HH,
                                               outR, 0, 0, sparse, e0,
                                               lists + (size_t)e0 * NN, cnt8 + e0);
    }
    combine_kernel<<<NN * HH / 8 / 256, 256, 0, stream>>>(outR, out);
}